// Round 2
// baseline (2393.820 us; speedup 1.0000x reference)
//
#include <hip/hip_runtime.h>

#define B_ 16
#define N_ 4096
#define S_ 1024
#define K_ 32
#define GS 133   // LDS row stride (pad from 128/131) -> conflict-free strided reads

typedef unsigned long long u64;

__device__ __forceinline__ unsigned short f2bf(float f) {
  unsigned u = __float_as_uint(f);
  unsigned r = (u + 0x7FFFu + ((u >> 16) & 1u)) >> 16;
  return (unsigned short)r;
}
__device__ __forceinline__ float bf2f(unsigned short h) {
  return __uint_as_float(((unsigned)h) << 16);
}

// ---------------- init: zero stats, transpose weights ----------------
__global__ void k_init(const float* __restrict__ w0, const float* __restrict__ w1,
                       const float* __restrict__ w2, float* __restrict__ wT0,
                       float* __restrict__ wT1, float* __restrict__ wT2,
                       float* __restrict__ stats) {
  int t = blockIdx.x * blockDim.x + threadIdx.x;
  int st = gridDim.x * blockDim.x;
  for (int i = t; i < 32768; i += st) stats[i] = 0.0f;
  for (int i = t; i < 128 * 131; i += st) { int o = i / 131; int c = i - o * 131; wT0[c * 128 + o] = w0[i]; }
  for (int i = t; i < 128 * 128; i += st) { int o = i >> 7; int c = i & 127; wT1[c * 128 + o] = w1[i]; }
  for (int i = t; i < 256 * 128; i += st) { int o = i >> 7; int c = i & 127; wT2[c * 256 + o] = w2[i]; }
}

// ---------------- farthest point sampling ----------------
// One block per batch. Points in registers (16/thread); LDS copy only for
// centroid lookup. Distance = ((dx*dx + dy*dy) + dz*dz), no fma (match np).
// Argmax tie-break: first (lowest) index, via packed key.
__global__ __launch_bounds__(256) void k_fps(const float* __restrict__ xyz,
                                             float* __restrict__ new_xyz) {
  __shared__ float sx[N_], sy[N_], sz[N_];
  __shared__ u64 swk[4];
  __shared__ int s_cur;
  int b = blockIdx.x, t = threadIdx.x;
  const float* base = xyz + (size_t)b * N_ * 3;
  for (int i = t; i < N_; i += 256) {
    sx[i] = base[i * 3]; sy[i] = base[i * 3 + 1]; sz[i] = base[i * 3 + 2];
  }
  __syncthreads();
  float px[16], py[16], pz[16], pd[16];
  int i0 = t * 16;
  #pragma unroll
  for (int j = 0; j < 16; ++j) {
    px[j] = sx[i0 + j]; py[j] = sy[i0 + j]; pz[j] = sz[i0 + j];
    pd[j] = 1e10f;
  }
  int cur = 0;
  for (int it = 0; it < S_; ++it) {
    if (t == 0) {
      size_t o = ((size_t)b * S_ + it) * 3;
      new_xyz[o] = sx[cur]; new_xyz[o + 1] = sy[cur]; new_xyz[o + 2] = sz[cur];
    }
    float cx = sx[cur], cy = sy[cur], cz = sz[cur];
    float bestv = -1.0f; int besti = 0;
    #pragma unroll
    for (int j = 0; j < 16; ++j) {
      float dx = px[j] - cx, dy = py[j] - cy, dz = pz[j] - cz;
      float d = __fadd_rn(__fadd_rn(__fmul_rn(dx, dx), __fmul_rn(dy, dy)), __fmul_rn(dz, dz));
      float dm = fminf(pd[j], d);
      pd[j] = dm;
      if (dm > bestv) { bestv = dm; besti = j; }
    }
    u64 key = ((u64)__float_as_uint(bestv) << 32) | (unsigned)(4095 - (i0 + besti));
    #pragma unroll
    for (int d = 32; d; d >>= 1) {
      u64 o = __shfl_down(key, (unsigned)d);
      if (o > key) key = o;
    }
    if ((t & 63) == 0) swk[t >> 6] = key;
    __syncthreads();
    if (t == 0) {
      u64 k = swk[0];
      if (swk[1] > k) k = swk[1];
      if (swk[2] > k) k = swk[2];
      if (swk[3] > k) k = swk[3];
      s_cur = 4095 - (int)(unsigned)(k & 0xFFFFFFFFull);
    }
    __syncthreads();
    cur = s_cur;
  }
}

// ---------------- transpose features (B,C,N) -> (B,N,C) ----------------
__global__ __launch_bounds__(256) void k_transpose(const float* __restrict__ f,
                                                   float* __restrict__ ft) {
  __shared__ float tile[32][33];
  int b = blockIdx.z;
  int n0 = blockIdx.x * 32, c0 = blockIdx.y * 32;
  int tx = threadIdx.x, ty = threadIdx.y;
  #pragma unroll
  for (int j = 0; j < 32; j += 8)
    tile[ty + j][tx] = f[((size_t)b * 128 + c0 + ty + j) * N_ + n0 + tx];
  __syncthreads();
  #pragma unroll
  for (int j = 0; j < 32; j += 8)
    ft[((size_t)b * N_ + n0 + ty + j) * 128 + c0 + tx] = tile[tx][ty + j];
}

// ---------------- ball query: first 32 ascending indices within r^2 -------
// One wave per query; distance uses the reference's -2*dot + |s|^2 + |d|^2
// formula with matching add order (no fma).
__global__ __launch_bounds__(256) void k_ballq(const float* __restrict__ xyz,
                                               const float* __restrict__ new_xyz,
                                               int* __restrict__ ball_idx) {
  int b = blockIdx.y;
  int s = blockIdx.x * 4 + (threadIdx.x >> 6);
  int lane = threadIdx.x & 63;
  const float* pb = xyz + (size_t)b * N_ * 3;
  size_t q = (size_t)b * S_ + s;
  float qx = new_xyz[q * 3], qy = new_xyz[q * 3 + 1], qz = new_xyz[q * 3 + 2];
  float sq = __fadd_rn(__fadd_rn(__fmul_rn(qx, qx), __fmul_rn(qy, qy)), __fmul_rn(qz, qz));
  int* out = ball_idx + q * K_;
  int total = 0;
  int first_idx = -1;
  for (int basei = 0; basei < N_; basei += 64) {
    int i = basei + lane;
    float fx = pb[i * 3], fy = pb[i * 3 + 1], fz = pb[i * 3 + 2];
    float dot = __fmul_rn(qx, fx);
    dot = __fadd_rn(dot, __fmul_rn(qy, fy));
    dot = __fadd_rn(dot, __fmul_rn(qz, fz));
    float sd = __fadd_rn(__fadd_rn(__fmul_rn(fx, fx), __fmul_rn(fy, fy)), __fmul_rn(fz, fz));
    float dist = __fadd_rn(__fadd_rn(__fmul_rn(-2.0f, dot), sq), sd);
    bool within = (dist <= 0.36f);
    u64 m = __ballot(within);
    if (first_idx < 0 && m) first_idx = basei + __ffsll((long long)m) - 1;
    if (within) {
      int pos = total + __popcll(m & ((1ull << lane) - 1ull));
      if (pos < K_) out[pos] = i;
    }
    total += (int)__popcll(m);
    if (total >= K_) break;
  }
  if (total < K_) {
    int k2 = total + lane;
    if (k2 < K_) out[k2] = first_idx;
  }
}

// ---------------- layer 1: gather + matmul(131->128) + stats --------------
__global__ __launch_bounds__(256) void k_layer1(
    const float* __restrict__ xyz, const float* __restrict__ new_xyz,
    const float* __restrict__ featT, const int* __restrict__ ball_idx,
    const float* __restrict__ wT, const float* __restrict__ bias,
    unsigned short* __restrict__ yout, float* __restrict__ stats) {
  __shared__ float g[K_ * GS];
  int b = blockIdx.y, s = blockIdx.x, t = threadIdx.x;
  size_t q = (size_t)b * S_ + s;
  const int* idx = ball_idx + q * K_;
  {
    int k = t & 31, cg = t >> 5;
    int p = idx[k]; if (p < 0) p = 0;
    const float4* src = (const float4*)(featT + ((size_t)b * N_ + p) * 128 + cg * 16);
    float* grow = g + k * GS + 3 + cg * 16;
    #pragma unroll
    for (int j = 0; j < 4; ++j) {
      float4 v = src[j];
      grow[j * 4] = v.x; grow[j * 4 + 1] = v.y; grow[j * 4 + 2] = v.z; grow[j * 4 + 3] = v.w;
    }
    if (cg == 0) {
      const float* pp = xyz + ((size_t)b * N_ + p) * 3;
      g[k * GS]     = pp[0] - new_xyz[q * 3];
      g[k * GS + 1] = pp[1] - new_xyz[q * 3 + 1];
      g[k * GS + 2] = pp[2] - new_xyz[q * 3 + 2];
    }
  }
  __syncthreads();
  int o0 = (t >> 3) * 4, k0 = (t & 7) * 4;
  float acc[4][4];
  #pragma unroll
  for (int a = 0; a < 4; ++a)
    #pragma unroll
    for (int c = 0; c < 4; ++c) acc[a][c] = 0.0f;
  for (int c = 0; c < 131; ++c) {
    float4 w4 = *(const float4*)(wT + c * 128 + o0);
    float wv[4] = {w4.x, w4.y, w4.z, w4.w};
    float gv[4];
    #pragma unroll
    for (int kj = 0; kj < 4; ++kj) gv[kj] = g[(k0 + kj) * GS + c];
    #pragma unroll
    for (int oj = 0; oj < 4; ++oj)
      #pragma unroll
      for (int kj = 0; kj < 4; ++kj) acc[oj][kj] += wv[oj] * gv[kj];
  }
  float bo[4] = {bias[o0], bias[o0 + 1], bias[o0 + 2], bias[o0 + 3]};
  float s1[4] = {0, 0, 0, 0}, s2[4] = {0, 0, 0, 0};
  #pragma unroll
  for (int kj = 0; kj < 4; ++kj) {
    ushort4 pk;
    float y0 = acc[0][kj] + bo[0]; float y1v = acc[1][kj] + bo[1];
    float y2v = acc[2][kj] + bo[2]; float y3v = acc[3][kj] + bo[3];
    s1[0] += y0; s2[0] += y0 * y0; s1[1] += y1v; s2[1] += y1v * y1v;
    s1[2] += y2v; s2[2] += y2v * y2v; s1[3] += y3v; s2[3] += y3v * y3v;
    pk.x = f2bf(y0); pk.y = f2bf(y1v); pk.z = f2bf(y2v); pk.w = f2bf(y3v);
    *(ushort4*)(yout + (q * K_ + k0 + kj) * 128 + o0) = pk;
  }
  #pragma unroll
  for (int d = 4; d; d >>= 1) {
    #pragma unroll
    for (int oj = 0; oj < 4; ++oj) {
      s1[oj] += __shfl_down(s1[oj], (unsigned)d);
      s2[oj] += __shfl_down(s2[oj], (unsigned)d);
    }
  }
  if ((t & 7) == 0) {
    int slot = blockIdx.x & 31;
    #pragma unroll
    for (int oj = 0; oj < 4; ++oj) {
      atomicAdd(stats + ((size_t)slot * 128 + o0 + oj) * 2, s1[oj]);
      atomicAdd(stats + ((size_t)slot * 128 + o0 + oj) * 2 + 1, s2[oj]);
    }
  }
}

// ---------------- finalize BN stats -> a=gamma*rsig, d=beta-a*mu ----------
__global__ void k_finalize(const float* __restrict__ stats, const float* __restrict__ gamma,
                           const float* __restrict__ beta, float* __restrict__ murs, int C) {
  for (int c = threadIdx.x; c < C; c += blockDim.x) {
    float s1 = 0.0f, s2 = 0.0f;
    for (int sl = 0; sl < 32; ++sl) {
      s1 += stats[((size_t)sl * C + c) * 2];
      s2 += stats[((size_t)sl * C + c) * 2 + 1];
    }
    const float inv = 1.0f / 524288.0f;  // 2^-19, exact
    float mu = s1 * inv;
    float var = s2 * inv - mu * mu;
    float a = gamma[c] * rsqrtf(var + 1e-5f);
    murs[c * 2] = a;
    murs[c * 2 + 1] = beta[c] - a * mu;
  }
}

// ---------------- layer 2: BN+relu(y) -> matmul(128->128), y IN-PLACE ----
// In-place safe: each block stages its full (b,s) slice of y into LDS
// (all reads) before __syncthreads, then overwrites the same slice.
__global__ __launch_bounds__(256) void k_layer2(
    unsigned short* y, const float* __restrict__ murs,
    const float* __restrict__ wT, const float* __restrict__ bias,
    float* __restrict__ stats) {
  __shared__ float g[K_ * GS];
  __shared__ float sa[128], sd[128];
  int b = blockIdx.y, s = blockIdx.x, t = threadIdx.x;
  size_t q = (size_t)b * S_ + s;
  if (t < 128) { sa[t] = murs[t * 2]; sd[t] = murs[t * 2 + 1]; }
  __syncthreads();
  {
    int k = t & 31, cg = t >> 5;
    const unsigned short* yr = y + (q * K_ + k) * 128 + cg * 16;
    float* grow = g + k * GS + cg * 16;
    int cb = cg * 16;
    #pragma unroll
    for (int j = 0; j < 4; ++j) {
      ushort4 pk = *(const ushort4*)(yr + j * 4);
      grow[j * 4]     = fmaxf(sa[cb + j * 4]     * bf2f(pk.x) + sd[cb + j * 4], 0.0f);
      grow[j * 4 + 1] = fmaxf(sa[cb + j * 4 + 1] * bf2f(pk.y) + sd[cb + j * 4 + 1], 0.0f);
      grow[j * 4 + 2] = fmaxf(sa[cb + j * 4 + 2] * bf2f(pk.z) + sd[cb + j * 4 + 2], 0.0f);
      grow[j * 4 + 3] = fmaxf(sa[cb + j * 4 + 3] * bf2f(pk.w) + sd[cb + j * 4 + 3], 0.0f);
    }
  }
  __syncthreads();
  int o0 = (t >> 3) * 4, k0 = (t & 7) * 4;
  float acc[4][4];
  #pragma unroll
  for (int a = 0; a < 4; ++a)
    #pragma unroll
    for (int c = 0; c < 4; ++c) acc[a][c] = 0.0f;
  for (int c = 0; c < 128; ++c) {
    float4 w4 = *(const float4*)(wT + c * 128 + o0);
    float wv[4] = {w4.x, w4.y, w4.z, w4.w};
    float gv[4];
    #pragma unroll
    for (int kj = 0; kj < 4; ++kj) gv[kj] = g[(k0 + kj) * GS + c];
    #pragma unroll
    for (int oj = 0; oj < 4; ++oj)
      #pragma unroll
      for (int kj = 0; kj < 4; ++kj) acc[oj][kj] += wv[oj] * gv[kj];
  }
  float bo[4] = {bias[o0], bias[o0 + 1], bias[o0 + 2], bias[o0 + 3]};
  float s1[4] = {0, 0, 0, 0}, s2[4] = {0, 0, 0, 0};
  #pragma unroll
  for (int kj = 0; kj < 4; ++kj) {
    ushort4 pk;
    float y0 = acc[0][kj] + bo[0]; float y1v = acc[1][kj] + bo[1];
    float y2v = acc[2][kj] + bo[2]; float y3v = acc[3][kj] + bo[3];
    s1[0] += y0; s2[0] += y0 * y0; s1[1] += y1v; s2[1] += y1v * y1v;
    s1[2] += y2v; s2[2] += y2v * y2v; s1[3] += y3v; s2[3] += y3v * y3v;
    pk.x = f2bf(y0); pk.y = f2bf(y1v); pk.z = f2bf(y2v); pk.w = f2bf(y3v);
    *(ushort4*)(y + (q * K_ + k0 + kj) * 128 + o0) = pk;
  }
  #pragma unroll
  for (int d = 4; d; d >>= 1) {
    #pragma unroll
    for (int oj = 0; oj < 4; ++oj) {
      s1[oj] += __shfl_down(s1[oj], (unsigned)d);
      s2[oj] += __shfl_down(s2[oj], (unsigned)d);
    }
  }
  if ((t & 7) == 0) {
    int slot = blockIdx.x & 31;
    #pragma unroll
    for (int oj = 0; oj < 4; ++oj) {
      atomicAdd(stats + ((size_t)slot * 128 + o0 + oj) * 2, s1[oj]);
      atomicAdd(stats + ((size_t)slot * 128 + o0 + oj) * 2 + 1, s2[oj]);
    }
  }
}

// ------- layer 3: BN+relu(y) -> matmul(128->256), track max/min over k ---
// BN+relu are monotone per-channel, so maxpool commutes: store only
// ymax/ymin per (b,s,o) (bf16) instead of the full 268 MB y3 tensor.
__global__ __launch_bounds__(256) void k_layer3(
    const unsigned short* __restrict__ yin, const float* __restrict__ murs,
    const float* __restrict__ wT, const float* __restrict__ bias,
    unsigned short* __restrict__ ymax, unsigned short* __restrict__ ymin,
    float* __restrict__ stats) {
  __shared__ float g[K_ * GS];
  __shared__ float sa[128], sd[128];
  int b = blockIdx.y, s = blockIdx.x, t = threadIdx.x;
  size_t q = (size_t)b * S_ + s;
  if (t < 128) { sa[t] = murs[t * 2]; sd[t] = murs[t * 2 + 1]; }
  __syncthreads();
  {
    int k = t & 31, cg = t >> 5;
    const unsigned short* yr = yin + (q * K_ + k) * 128 + cg * 16;
    float* grow = g + k * GS + cg * 16;
    int cb = cg * 16;
    #pragma unroll
    for (int j = 0; j < 4; ++j) {
      ushort4 pk = *(const ushort4*)(yr + j * 4);
      grow[j * 4]     = fmaxf(sa[cb + j * 4]     * bf2f(pk.x) + sd[cb + j * 4], 0.0f);
      grow[j * 4 + 1] = fmaxf(sa[cb + j * 4 + 1] * bf2f(pk.y) + sd[cb + j * 4 + 1], 0.0f);
      grow[j * 4 + 2] = fmaxf(sa[cb + j * 4 + 2] * bf2f(pk.z) + sd[cb + j * 4 + 2], 0.0f);
      grow[j * 4 + 3] = fmaxf(sa[cb + j * 4 + 3] * bf2f(pk.w) + sd[cb + j * 4 + 3], 0.0f);
    }
  }
  __syncthreads();
  int o0 = (t >> 3) * 8, k0 = (t & 7) * 4;
  float acc[8][4];
  #pragma unroll
  for (int a = 0; a < 8; ++a)
    #pragma unroll
    for (int c = 0; c < 4; ++c) acc[a][c] = 0.0f;
  for (int c = 0; c < 128; ++c) {
    float4 wa = *(const float4*)(wT + c * 256 + o0);
    float4 wb = *(const float4*)(wT + c * 256 + o0 + 4);
    float wv[8] = {wa.x, wa.y, wa.z, wa.w, wb.x, wb.y, wb.z, wb.w};
    float gv[4];
    #pragma unroll
    for (int kj = 0; kj < 4; ++kj) gv[kj] = g[(k0 + kj) * GS + c];
    #pragma unroll
    for (int oj = 0; oj < 8; ++oj)
      #pragma unroll
      for (int kj = 0; kj < 4; ++kj) acc[oj][kj] += wv[oj] * gv[kj];
  }
  float s1v[8], s2v[8], tmx[8], tmn[8];
  #pragma unroll
  for (int oj = 0; oj < 8; ++oj) {
    float bo = bias[o0 + oj];
    float mx = -3.4e38f, mn = 3.4e38f, a1 = 0.0f, a2 = 0.0f;
    #pragma unroll
    for (int kj = 0; kj < 4; ++kj) {
      float yv = acc[oj][kj] + bo;
      a1 += yv; a2 += yv * yv;
      mx = fmaxf(mx, yv); mn = fminf(mn, yv);
    }
    s1v[oj] = a1; s2v[oj] = a2; tmx[oj] = mx; tmn[oj] = mn;
  }
  #pragma unroll
  for (int d = 4; d; d >>= 1) {
    #pragma unroll
    for (int oj = 0; oj < 8; ++oj) {
      s1v[oj] += __shfl_down(s1v[oj], (unsigned)d);
      s2v[oj] += __shfl_down(s2v[oj], (unsigned)d);
      tmx[oj] = fmaxf(tmx[oj], __shfl_down(tmx[oj], (unsigned)d));
      tmn[oj] = fminf(tmn[oj], __shfl_down(tmn[oj], (unsigned)d));
    }
  }
  if ((t & 7) == 0) {
    int slot = blockIdx.x & 31;
    #pragma unroll
    for (int oj = 0; oj < 8; ++oj) {
      ymax[q * 256 + o0 + oj] = f2bf(tmx[oj]);
      ymin[q * 256 + o0 + oj] = f2bf(tmn[oj]);
      atomicAdd(stats + ((size_t)slot * 256 + o0 + oj) * 2, s1v[oj]);
      atomicAdd(stats + ((size_t)slot * 256 + o0 + oj) * 2 + 1, s2v[oj]);
    }
  }
}

// -------- final: select extreme by sign(a), BN+relu, transpose to (b,o,s) --
__global__ __launch_bounds__(256) void k_final(const unsigned short* __restrict__ ymax,
                                               const unsigned short* __restrict__ ymin,
                                               const float* __restrict__ murs,
                                               float* __restrict__ out2) {
  __shared__ float tile[32][33];
  int b = blockIdx.z, o0 = blockIdx.y * 32, s0 = blockIdx.x * 32;
  int tx = threadIdx.x, ty = threadIdx.y;
  float a_rd = murs[(o0 + tx) * 2];
  #pragma unroll
  for (int j = 0; j < 32; j += 8) {
    size_t src = ((size_t)b * S_ + s0 + ty + j) * 256 + o0 + tx;
    tile[ty + j][tx] = (a_rd >= 0.0f) ? bf2f(ymax[src]) : bf2f(ymin[src]);
  }
  __syncthreads();
  #pragma unroll
  for (int j = 0; j < 32; j += 8) {
    int o = o0 + ty + j;
    float a = murs[o * 2], dd = murs[o * 2 + 1];
    out2[((size_t)b * 256 + o) * S_ + s0 + tx] = fmaxf(a * tile[tx][ty + j] + dd, 0.0f);
  }
}

extern "C" void kernel_launch(void* const* d_in, const int* in_sizes, int n_in,
                              void* d_out, int out_size, void* d_ws, size_t ws_size,
                              hipStream_t stream) {
  (void)in_sizes; (void)n_in; (void)out_size; (void)ws_size;
  const float* xyz  = (const float*)d_in[0];
  const float* feat = (const float*)d_in[1];
  const float* w0   = (const float*)d_in[2];
  const float* b0   = (const float*)d_in[3];
  const float* ga0  = (const float*)d_in[4];
  const float* be0  = (const float*)d_in[5];
  const float* w1   = (const float*)d_in[6];
  const float* b1   = (const float*)d_in[7];
  const float* ga1  = (const float*)d_in[8];
  const float* be1  = (const float*)d_in[9];
  const float* w2   = (const float*)d_in[10];
  const float* b2   = (const float*)d_in[11];
  const float* ga2  = (const float*)d_in[12];
  const float* be2  = (const float*)d_in[13];

  float* out_xyz  = (float*)d_out;
  float* out_feat = out_xyz + (size_t)B_ * S_ * 3;

  char* ws = (char*)d_ws;
  size_t off = 0;
  auto alloc = [&](size_t bytes) -> void* {
    void* p = ws + off;
    off += (bytes + 255) & ~(size_t)255;
    return p;
  };
  // Total workspace: ~187 MB (was 338 MB in round 1 -> suspected ws overflow)
  float* featT = (float*)alloc((size_t)B_ * N_ * 128 * 4);            // 33.6 MB
  float* wT0   = (float*)alloc(131 * 128 * 4);
  float* wT1   = (float*)alloc(128 * 128 * 4);
  float* wT2   = (float*)alloc(128 * 256 * 4);
  int*   ball  = (int*)alloc((size_t)B_ * S_ * K_ * 4);               // 2.1 MB
  float* stats = (float*)alloc(32768 * 4);
  float* murs1 = (float*)alloc(128 * 2 * 4);
  float* murs2 = (float*)alloc(128 * 2 * 4);
  float* murs3 = (float*)alloc(256 * 2 * 4);
  unsigned short* ymaxb = (unsigned short*)alloc((size_t)B_ * S_ * 256 * 2);  // 8.4 MB
  unsigned short* yminb = (unsigned short*)alloc((size_t)B_ * S_ * 256 * 2);  // 8.4 MB
  unsigned short* y = (unsigned short*)alloc((size_t)B_ * S_ * K_ * 128 * 2); // 134 MB (y1, then y2 in-place)

  k_init<<<64, 256, 0, stream>>>(w0, w1, w2, wT0, wT1, wT2, stats);
  k_fps<<<16, 256, 0, stream>>>(xyz, out_xyz);
  k_transpose<<<dim3(128, 4, 16), dim3(32, 8), 0, stream>>>(feat, featT);
  k_ballq<<<dim3(256, 16), 256, 0, stream>>>(xyz, out_xyz, ball);
  k_layer1<<<dim3(1024, 16), 256, 0, stream>>>(xyz, out_xyz, featT, ball, wT0, b0, y, stats);
  k_finalize<<<1, 256, 0, stream>>>(stats, ga0, be0, murs1, 128);
  k_layer2<<<dim3(1024, 16), 256, 0, stream>>>(y, murs1, wT1, b1, stats + 8192);
  k_finalize<<<1, 256, 0, stream>>>(stats + 8192, ga1, be1, murs2, 128);
  k_layer3<<<dim3(1024, 16), 256, 0, stream>>>(y, murs2, wT2, b2, ymaxb, yminb, stats + 16384);
  k_finalize<<<1, 256, 0, stream>>>(stats + 16384, ga2, be2, murs3, 256);
  k_final<<<dim3(32, 8, 16), dim3(32, 8), 0, stream>>>(ymaxb, yminb, murs3, out_feat);
}

// Round 3
// 1545.193 us; speedup vs baseline: 1.5492x; 1.5492x over previous
//
#include <hip/hip_runtime.h>

#define B_ 16
#define N_ 4096
#define S_ 1024
#define K_ 32
#define PITCH2 136   // 128 + 8 shorts: b128 frag reads -> 2-way bank alias (free)
#define PITCH1 168   // 160 + 8 shorts

typedef unsigned long long u64;
typedef short bf16x8 __attribute__((ext_vector_type(8)));   // 8 bf16 = 4 VGPR (guide §3)
typedef float f32x4 __attribute__((ext_vector_type(4)));

__device__ __forceinline__ unsigned short f2bf(float f) {
  unsigned u = __float_as_uint(f);
  unsigned r = (u + 0x7FFFu + ((u >> 16) & 1u)) >> 16;
  return (unsigned short)r;
}
__device__ __forceinline__ float bf2f(unsigned short h) {
  return __uint_as_float(((unsigned)h) << 16);
}

// ---------------- init: zero stats ----------------
__global__ void k_init(float* __restrict__ stats) {
  int t = blockIdx.x * blockDim.x + threadIdx.x;
  if (t < 32768) stats[t] = 0.0f;
}

// ---------------- farthest point sampling ----------------
// One block per batch; points in registers (16/thread). Distance math kept
// bit-exact vs numpy: ((dx*dx+dy*dy)+dz*dz), rn mul/add, no fma.
// ONE barrier/iter: f32 butterfly max + ballot owner-pick (tie -> lowest idx),
// double-buffered swk removes the WAR hazard on the cross-wave keys.
__global__ __launch_bounds__(256) void k_fps(const float* __restrict__ xyz,
                                             float* __restrict__ new_xyz) {
  __shared__ float sx[N_], sy[N_], sz[N_];
  __shared__ u64 swk[2][4];
  int b = blockIdx.x, t = threadIdx.x;
  const float* base = xyz + (size_t)b * N_ * 3;
  for (int i = t; i < N_; i += 256) {
    sx[i] = base[i * 3]; sy[i] = base[i * 3 + 1]; sz[i] = base[i * 3 + 2];
  }
  __syncthreads();
  float px[16], py[16], pz[16], pd[16];
  int i0 = t * 16;
  #pragma unroll
  for (int j = 0; j < 16; ++j) {
    px[j] = sx[i0 + j]; py[j] = sy[i0 + j]; pz[j] = sz[i0 + j];
    pd[j] = 1e10f;
  }
  int cur = 0;
  for (int it = 0; it < S_; ++it) {
    if (t == 0) {
      size_t o = ((size_t)b * S_ + it) * 3;
      new_xyz[o] = sx[cur]; new_xyz[o + 1] = sy[cur]; new_xyz[o + 2] = sz[cur];
    }
    float cx = sx[cur], cy = sy[cur], cz = sz[cur];
    float bestv = -1.0f; int besti = 0;
    #pragma unroll
    for (int j = 0; j < 16; ++j) {
      float dx = px[j] - cx, dy = py[j] - cy, dz = pz[j] - cz;
      float d = __fadd_rn(__fadd_rn(__fmul_rn(dx, dx), __fmul_rn(dy, dy)), __fmul_rn(dz, dz));
      float dm = fminf(pd[j], d);
      pd[j] = dm;
      if (dm > bestv) { bestv = dm; besti = j; }
    }
    float wmax = bestv;
    #pragma unroll
    for (int d = 1; d < 64; d <<= 1) wmax = fmaxf(wmax, __shfl_xor(wmax, d));
    u64 mask = __ballot(bestv == wmax);
    int owner = __ffsll((long long)mask) - 1;
    int cand = i0 + besti;
    int widx = __shfl(cand, owner);
    if ((t & 63) == 0)
      swk[it & 1][t >> 6] = ((u64)__float_as_uint(wmax) << 32) | (unsigned)(4095 - widx);
    __syncthreads();
    const u64* kk = swk[it & 1];
    u64 k0 = kk[0];
    if (kk[1] > k0) k0 = kk[1];
    if (kk[2] > k0) k0 = kk[2];
    if (kk[3] > k0) k0 = kk[3];
    cur = 4095 - (int)(unsigned)(k0 & 0xFFFFFFFFull);
  }
}

// ---------------- transpose features (B,C,N) f32 -> (B,N,C) bf16 ----------
__global__ __launch_bounds__(256) void k_transpose(const float* __restrict__ f,
                                                   unsigned short* __restrict__ ft) {
  __shared__ float tile[32][33];
  int b = blockIdx.z;
  int n0 = blockIdx.x * 32, c0 = blockIdx.y * 32;
  int tx = threadIdx.x, ty = threadIdx.y;
  #pragma unroll
  for (int j = 0; j < 32; j += 8)
    tile[ty + j][tx] = f[((size_t)b * 128 + c0 + ty + j) * N_ + n0 + tx];
  __syncthreads();
  #pragma unroll
  for (int j = 0; j < 32; j += 8)
    ft[((size_t)b * N_ + n0 + ty + j) * 128 + c0 + tx] = f2bf(tile[tx][ty + j]);
}

// ---------------- ball query (unchanged, bit-exact formula) ----------------
__global__ __launch_bounds__(256) void k_ballq(const float* __restrict__ xyz,
                                               const float* __restrict__ new_xyz,
                                               int* __restrict__ ball_idx) {
  int b = blockIdx.y;
  int s = blockIdx.x * 4 + (threadIdx.x >> 6);
  int lane = threadIdx.x & 63;
  const float* pb = xyz + (size_t)b * N_ * 3;
  size_t q = (size_t)b * S_ + s;
  float qx = new_xyz[q * 3], qy = new_xyz[q * 3 + 1], qz = new_xyz[q * 3 + 2];
  float sq = __fadd_rn(__fadd_rn(__fmul_rn(qx, qx), __fmul_rn(qy, qy)), __fmul_rn(qz, qz));
  int* out = ball_idx + q * K_;
  int total = 0;
  int first_idx = -1;
  for (int basei = 0; basei < N_; basei += 64) {
    int i = basei + lane;
    float fx = pb[i * 3], fy = pb[i * 3 + 1], fz = pb[i * 3 + 2];
    float dot = __fmul_rn(qx, fx);
    dot = __fadd_rn(dot, __fmul_rn(qy, fy));
    dot = __fadd_rn(dot, __fmul_rn(qz, fz));
    float sd = __fadd_rn(__fadd_rn(__fmul_rn(fx, fx), __fmul_rn(fy, fy)), __fmul_rn(fz, fz));
    float dist = __fadd_rn(__fadd_rn(__fmul_rn(-2.0f, dot), sq), sd);
    bool within = (dist <= 0.36f);
    u64 m = __ballot(within);
    if (first_idx < 0 && m) first_idx = basei + __ffsll((long long)m) - 1;
    if (within) {
      int pos = total + __popcll(m & ((1ull << lane) - 1ull));
      if (pos < K_) out[pos] = i;
    }
    total += (int)__popcll(m);
    if (total >= K_) break;
  }
  if (total < K_) {
    int k2 = total + lane;
    if (k2 < K_) out[k2] = first_idx;
  }
}

// ============ MFMA layer kernels ============
// Per block: M=128 rows (4 queries x 32 samples), N=128 cols, K in LDS.
// Wave w <-> query w (M-tiles 2w, 2w+1). A-frag: G[m][k0..k0+7] b128 read;
// B-frag: W[n][k0..k0+7] b128 read. D: col=lane&15, row=(lane>>4)*4+reg.

#define MFMA(a, b, c) __builtin_amdgcn_mfma_f32_16x16x32_bf16(a, b, c, 0, 0, 0)

// ---- layer 1: gather + matmul K=131(pad 160) -> 128, channel-permuted ----
// k-permutation (same in G and W): feat -> 0..127, xyz -> 128..130, pad->159.
__global__ __launch_bounds__(256) void k_layer1(
    const float* __restrict__ xyz, const float* __restrict__ new_xyz,
    const unsigned short* __restrict__ featT, const int* __restrict__ ball_idx,
    const float* __restrict__ w0, const float* __restrict__ b0,
    unsigned short* __restrict__ y, float* __restrict__ stats) {
  __shared__ __align__(16) unsigned short Wl[128 * PITCH1];
  __shared__ __align__(16) unsigned short Gl[128 * PITCH1];
  __shared__ float sbias[128];
  int bb = blockIdx.y, s0 = blockIdx.x * 4, t = threadIdx.x;
  {
    int n = t >> 1, h = t & 1;
    const float* wr = w0 + n * 131;
    for (int k = h * 80; k < h * 80 + 80; ++k) {
      float v = (k < 128) ? wr[3 + k] : (k < 131) ? wr[k - 128] : 0.0f;
      Wl[n * PITCH1 + k] = f2bf(v);
    }
    if (t < 128) sbias[t] = b0[t];
  }
  {
    int r = t >> 1, h = t & 1;
    int q = r >> 5, ks = r & 31;
    size_t qg = (size_t)bb * S_ + s0 + q;
    int p = ball_idx[qg * K_ + ks]; if (p < 0) p = 0;
    const uint4* fr = (const uint4*)(featT + ((size_t)bb * N_ + p) * 128 + h * 64);
    uint4* gr = (uint4*)(Gl + r * PITCH1 + h * 64);
    #pragma unroll
    for (int i = 0; i < 8; ++i) gr[i] = fr[i];   // straight bf16 copy (16B)
    if (h == 0) {
      const float* pp = xyz + ((size_t)bb * N_ + p) * 3;
      Gl[r * PITCH1 + 128] = f2bf(pp[0] - new_xyz[qg * 3]);
      Gl[r * PITCH1 + 129] = f2bf(pp[1] - new_xyz[qg * 3 + 1]);
      Gl[r * PITCH1 + 130] = f2bf(pp[2] - new_xyz[qg * 3 + 2]);
    } else {
      for (int k = 131; k < 160; ++k) Gl[r * PITCH1 + k] = 0;
    }
  }
  __syncthreads();
  int w = t >> 6, L = t & 63, lm = L & 15, lg = L >> 4;
  f32x4 acc[2][8];
  #pragma unroll
  for (int mi = 0; mi < 2; ++mi)
    #pragma unroll
    for (int nt = 0; nt < 8; ++nt) acc[mi][nt] = (f32x4){0.f, 0.f, 0.f, 0.f};
  for (int kt = 0; kt < 5; ++kt) {
    int ko = kt * 32 + lg * 8;
    bf16x8 a0 = *(const bf16x8*)&Gl[(w * 32 + lm) * PITCH1 + ko];
    bf16x8 a1 = *(const bf16x8*)&Gl[(w * 32 + 16 + lm) * PITCH1 + ko];
    bf16x8 bv[8];
    #pragma unroll
    for (int nt = 0; nt < 8; ++nt)
      bv[nt] = *(const bf16x8*)&Wl[(nt * 16 + lm) * PITCH1 + ko];
    #pragma unroll
    for (int nt = 0; nt < 8; ++nt) {
      acc[0][nt] = MFMA(a0, bv[nt], acc[0][nt]);
      acc[1][nt] = MFMA(a1, bv[nt], acc[1][nt]);
    }
  }
  size_t qg = (size_t)bb * S_ + s0 + w;
  int slot = blockIdx.x & 31;
  #pragma unroll
  for (int nt = 0; nt < 8; ++nt) {
    int col = nt * 16 + lm;
    float bo = sbias[col];
    float s1 = 0.f, s2 = 0.f;
    #pragma unroll
    for (int mi = 0; mi < 2; ++mi)
      #pragma unroll
      for (int r = 0; r < 4; ++r) {
        float yv = acc[mi][nt][r] + bo;
        s1 += yv; s2 += yv * yv;
        int ks = mi * 16 + lg * 4 + r;
        y[(qg * K_ + ks) * 128 + col] = f2bf(yv);
      }
    s1 += __shfl_xor(s1, 16); s2 += __shfl_xor(s2, 16);
    s1 += __shfl_xor(s1, 32); s2 += __shfl_xor(s2, 32);
    if (lg == 0) {
      atomicAdd(stats + ((size_t)slot * 128 + col) * 2, s1);
      atomicAdd(stats + ((size_t)slot * 128 + col) * 2 + 1, s2);
    }
  }
}

// ---------------- finalize BN stats -> a=gamma*rsig, d=beta-a*mu ----------
__global__ void k_finalize(const float* __restrict__ stats, const float* __restrict__ gamma,
                           const float* __restrict__ beta, float* __restrict__ murs, int C) {
  for (int c = threadIdx.x; c < C; c += blockDim.x) {
    float s1 = 0.0f, s2 = 0.0f;
    for (int sl = 0; sl < 32; ++sl) {
      s1 += stats[((size_t)sl * C + c) * 2];
      s2 += stats[((size_t)sl * C + c) * 2 + 1];
    }
    const float inv = 1.0f / 524288.0f;  // 2^-19, exact
    float mu = s1 * inv;
    float var = s2 * inv - mu * mu;
    float a = gamma[c] * rsqrtf(var + 1e-5f);
    murs[c * 2] = a;
    murs[c * 2 + 1] = beta[c] - a * mu;
  }
}

// ---- layer 2: BN+relu(y) -> matmul 128->128, y overwritten IN-PLACE ----
__global__ __launch_bounds__(256) void k_layer2(
    unsigned short* y, const float* __restrict__ murs,
    const float* __restrict__ w1, const float* __restrict__ b1,
    float* __restrict__ stats) {
  __shared__ __align__(16) unsigned short Wl[128 * PITCH2];
  __shared__ __align__(16) unsigned short Gl[128 * PITCH2];
  __shared__ float sa[128], sd[128], sbias[128];
  int bb = blockIdx.y, s0 = blockIdx.x * 4, t = threadIdx.x;
  {
    int n = t >> 1, h = t & 1;
    const float4* wr = (const float4*)(w1 + n * 128 + h * 64);
    #pragma unroll
    for (int i = 0; i < 16; ++i) {
      float4 v = wr[i];
      ushort4 pk = {f2bf(v.x), f2bf(v.y), f2bf(v.z), f2bf(v.w)};
      *(ushort4*)&Wl[n * PITCH2 + h * 64 + i * 4] = pk;
    }
    if (t < 128) { sa[t] = murs[t * 2]; sd[t] = murs[t * 2 + 1]; sbias[t] = b1[t]; }
  }
  __syncthreads();
  {
    int r = t >> 1, h = t & 1;
    int q = r >> 5, ks = r & 31;
    size_t qg = (size_t)bb * S_ + s0 + q;
    const ushort4* yr = (const ushort4*)(y + (qg * K_ + ks) * 128 + h * 64);
    #pragma unroll
    for (int i = 0; i < 16; ++i) {
      ushort4 p = yr[i];
      int c = h * 64 + i * 4;
      ushort4 pk;
      pk.x = f2bf(fmaxf(sa[c]     * bf2f(p.x) + sd[c],     0.f));
      pk.y = f2bf(fmaxf(sa[c + 1] * bf2f(p.y) + sd[c + 1], 0.f));
      pk.z = f2bf(fmaxf(sa[c + 2] * bf2f(p.z) + sd[c + 2], 0.f));
      pk.w = f2bf(fmaxf(sa[c + 3] * bf2f(p.w) + sd[c + 3], 0.f));
      *(ushort4*)&Gl[r * PITCH2 + c] = pk;
    }
  }
  __syncthreads();
  int w = t >> 6, L = t & 63, lm = L & 15, lg = L >> 4;
  f32x4 acc[2][8];
  #pragma unroll
  for (int mi = 0; mi < 2; ++mi)
    #pragma unroll
    for (int nt = 0; nt < 8; ++nt) acc[mi][nt] = (f32x4){0.f, 0.f, 0.f, 0.f};
  for (int kt = 0; kt < 4; ++kt) {
    int ko = kt * 32 + lg * 8;
    bf16x8 a0 = *(const bf16x8*)&Gl[(w * 32 + lm) * PITCH2 + ko];
    bf16x8 a1 = *(const bf16x8*)&Gl[(w * 32 + 16 + lm) * PITCH2 + ko];
    bf16x8 bv[8];
    #pragma unroll
    for (int nt = 0; nt < 8; ++nt)
      bv[nt] = *(const bf16x8*)&Wl[(nt * 16 + lm) * PITCH2 + ko];
    #pragma unroll
    for (int nt = 0; nt < 8; ++nt) {
      acc[0][nt] = MFMA(a0, bv[nt], acc[0][nt]);
      acc[1][nt] = MFMA(a1, bv[nt], acc[1][nt]);
    }
  }
  size_t qg = (size_t)bb * S_ + s0 + w;
  int slot = blockIdx.x & 31;
  #pragma unroll
  for (int nt = 0; nt < 8; ++nt) {
    int col = nt * 16 + lm;
    float bo = sbias[col];
    float s1 = 0.f, s2 = 0.f;
    #pragma unroll
    for (int mi = 0; mi < 2; ++mi)
      #pragma unroll
      for (int r = 0; r < 4; ++r) {
        float yv = acc[mi][nt][r] + bo;
        s1 += yv; s2 += yv * yv;
        int ks = mi * 16 + lg * 4 + r;
        y[(qg * K_ + ks) * 128 + col] = f2bf(yv);
      }
    s1 += __shfl_xor(s1, 16); s2 += __shfl_xor(s2, 16);
    s1 += __shfl_xor(s1, 32); s2 += __shfl_xor(s2, 32);
    if (lg == 0) {
      atomicAdd(stats + ((size_t)slot * 128 + col) * 2, s1);
      atomicAdd(stats + ((size_t)slot * 128 + col) * 2 + 1, s2);
    }
  }
}

// ---- layer 3: BN+relu(y) -> matmul 128->256 (N split by blockIdx.z),
//      maxpool commutes with monotone BN+relu -> store ymax/ymin only ----
__global__ __launch_bounds__(256) void k_layer3(
    const unsigned short* __restrict__ y, const float* __restrict__ murs,
    const float* __restrict__ w2, const float* __restrict__ b2,
    unsigned short* __restrict__ ymax, unsigned short* __restrict__ ymin,
    float* __restrict__ stats) {
  __shared__ __align__(16) unsigned short Wl[128 * PITCH2];
  __shared__ __align__(16) unsigned short Gl[128 * PITCH2];
  __shared__ float sa[128], sd[128], sbias[128];
  int bb = blockIdx.y, s0 = blockIdx.x * 4, nh = blockIdx.z, t = threadIdx.x;
  {
    int n = t >> 1, h = t & 1;
    const float4* wr = (const float4*)(w2 + (size_t)(nh * 128 + n) * 128 + h * 64);
    #pragma unroll
    for (int i = 0; i < 16; ++i) {
      float4 v = wr[i];
      ushort4 pk = {f2bf(v.x), f2bf(v.y), f2bf(v.z), f2bf(v.w)};
      *(ushort4*)&Wl[n * PITCH2 + h * 64 + i * 4] = pk;
    }
    if (t < 128) { sa[t] = murs[t * 2]; sd[t] = murs[t * 2 + 1]; sbias[t] = b2[nh * 128 + t]; }
  }
  __syncthreads();
  {
    int r = t >> 1, h = t & 1;
    int q = r >> 5, ks = r & 31;
    size_t qg = (size_t)bb * S_ + s0 + q;
    const ushort4* yr = (const ushort4*)(y + (qg * K_ + ks) * 128 + h * 64);
    #pragma unroll
    for (int i = 0; i < 16; ++i) {
      ushort4 p = yr[i];
      int c = h * 64 + i * 4;
      ushort4 pk;
      pk.x = f2bf(fmaxf(sa[c]     * bf2f(p.x) + sd[c],     0.f));
      pk.y = f2bf(fmaxf(sa[c + 1] * bf2f(p.y) + sd[c + 1], 0.f));
      pk.z = f2bf(fmaxf(sa[c + 2] * bf2f(p.z) + sd[c + 2], 0.f));
      pk.w = f2bf(fmaxf(sa[c + 3] * bf2f(p.w) + sd[c + 3], 0.f));
      *(ushort4*)&Gl[r * PITCH2 + c] = pk;
    }
  }
  __syncthreads();
  int w = t >> 6, L = t & 63, lm = L & 15, lg = L >> 4;
  f32x4 acc[2][8];
  #pragma unroll
  for (int mi = 0; mi < 2; ++mi)
    #pragma unroll
    for (int nt = 0; nt < 8; ++nt) acc[mi][nt] = (f32x4){0.f, 0.f, 0.f, 0.f};
  for (int kt = 0; kt < 4; ++kt) {
    int ko = kt * 32 + lg * 8;
    bf16x8 a0 = *(const bf16x8*)&Gl[(w * 32 + lm) * PITCH2 + ko];
    bf16x8 a1 = *(const bf16x8*)&Gl[(w * 32 + 16 + lm) * PITCH2 + ko];
    bf16x8 bv[8];
    #pragma unroll
    for (int nt = 0; nt < 8; ++nt)
      bv[nt] = *(const bf16x8*)&Wl[(nt * 16 + lm) * PITCH2 + ko];
    #pragma unroll
    for (int nt = 0; nt < 8; ++nt) {
      acc[0][nt] = MFMA(a0, bv[nt], acc[0][nt]);
      acc[1][nt] = MFMA(a1, bv[nt], acc[1][nt]);
    }
  }
  size_t qg = (size_t)bb * S_ + s0 + w;
  int slot = blockIdx.x & 31;
  #pragma unroll
  for (int nt = 0; nt < 8; ++nt) {
    int col = nt * 16 + lm;
    int o = nh * 128 + col;
    float bo = sbias[col];
    float s1 = 0.f, s2 = 0.f, mx = -3.4e38f, mn = 3.4e38f;
    #pragma unroll
    for (int mi = 0; mi < 2; ++mi)
      #pragma unroll
      for (int r = 0; r < 4; ++r) {
        float yv = acc[mi][nt][r] + bo;
        s1 += yv; s2 += yv * yv;
        mx = fmaxf(mx, yv); mn = fminf(mn, yv);
      }
    s1 += __shfl_xor(s1, 16); s2 += __shfl_xor(s2, 16);
    s1 += __shfl_xor(s1, 32); s2 += __shfl_xor(s2, 32);
    mx = fmaxf(mx, __shfl_xor(mx, 16)); mx = fmaxf(mx, __shfl_xor(mx, 32));
    mn = fminf(mn, __shfl_xor(mn, 16)); mn = fminf(mn, __shfl_xor(mn, 32));
    if (lg == 0) {
      ymax[qg * 256 + o] = f2bf(mx);
      ymin[qg * 256 + o] = f2bf(mn);
      atomicAdd(stats + ((size_t)slot * 256 + o) * 2, s1);
      atomicAdd(stats + ((size_t)slot * 256 + o) * 2 + 1, s2);
    }
  }
}

// -------- final: select extreme by sign(a), BN+relu, transpose to (b,o,s) --
__global__ __launch_bounds__(256) void k_final(const unsigned short* __restrict__ ymax,
                                               const unsigned short* __restrict__ ymin,
                                               const float* __restrict__ murs,
                                               float* __restrict__ out2) {
  __shared__ float tile[32][33];
  int b = blockIdx.z, o0 = blockIdx.y * 32, s0 = blockIdx.x * 32;
  int tx = threadIdx.x, ty = threadIdx.y;
  float a_rd = murs[(o0 + tx) * 2];
  #pragma unroll
  for (int j = 0; j < 32; j += 8) {
    size_t src = ((size_t)b * S_ + s0 + ty + j) * 256 + o0 + tx;
    tile[ty + j][tx] = (a_rd >= 0.0f) ? bf2f(ymax[src]) : bf2f(ymin[src]);
  }
  __syncthreads();
  #pragma unroll
  for (int j = 0; j < 32; j += 8) {
    int o = o0 + ty + j;
    float a = murs[o * 2], dd = murs[o * 2 + 1];
    out2[((size_t)b * 256 + o) * S_ + s0 + tx] = fmaxf(a * tile[tx][ty + j] + dd, 0.0f);
  }
}

extern "C" void kernel_launch(void* const* d_in, const int* in_sizes, int n_in,
                              void* d_out, int out_size, void* d_ws, size_t ws_size,
                              hipStream_t stream) {
  (void)in_sizes; (void)n_in; (void)out_size; (void)ws_size;
  const float* xyz  = (const float*)d_in[0];
  const float* feat = (const float*)d_in[1];
  const float* w0   = (const float*)d_in[2];
  const float* b0   = (const float*)d_in[3];
  const float* ga0  = (const float*)d_in[4];
  const float* be0  = (const float*)d_in[5];
  const float* w1   = (const float*)d_in[6];
  const float* b1   = (const float*)d_in[7];
  const float* ga1  = (const float*)d_in[8];
  const float* be1  = (const float*)d_in[9];
  const float* w2   = (const float*)d_in[10];
  const float* b2   = (const float*)d_in[11];
  const float* ga2  = (const float*)d_in[12];
  const float* be2  = (const float*)d_in[13];

  float* out_xyz  = (float*)d_out;
  float* out_feat = out_xyz + (size_t)B_ * S_ * 3;

  char* ws = (char*)d_ws;
  size_t off = 0;
  auto alloc = [&](size_t bytes) -> void* {
    void* p = ws + off;
    off += (bytes + 255) & ~(size_t)255;
    return p;
  };
  // Total ~170 MB
  unsigned short* featT = (unsigned short*)alloc((size_t)B_ * N_ * 128 * 2);  // 16.8 MB bf16
  int*   ball  = (int*)alloc((size_t)B_ * S_ * K_ * 4);                       // 2.1 MB
  float* stats = (float*)alloc(32768 * 4);
  float* murs1 = (float*)alloc(128 * 2 * 4);
  float* murs2 = (float*)alloc(128 * 2 * 4);
  float* murs3 = (float*)alloc(256 * 2 * 4);
  unsigned short* ymaxb = (unsigned short*)alloc((size_t)B_ * S_ * 256 * 2);  // 8.4 MB
  unsigned short* yminb = (unsigned short*)alloc((size_t)B_ * S_ * 256 * 2);  // 8.4 MB
  unsigned short* y = (unsigned short*)alloc((size_t)B_ * S_ * K_ * 128 * 2); // 134 MB (y1 then y2 in-place)

  k_init<<<128, 256, 0, stream>>>(stats);
  k_fps<<<16, 256, 0, stream>>>(xyz, out_xyz);
  k_transpose<<<dim3(128, 4, 16), dim3(32, 8), 0, stream>>>(feat, featT);
  k_ballq<<<dim3(256, 16), 256, 0, stream>>>(xyz, out_xyz, ball);
  k_layer1<<<dim3(256, 16), 256, 0, stream>>>(xyz, out_xyz, featT, ball, w0, b0, y, stats);
  k_finalize<<<1, 256, 0, stream>>>(stats, ga0, be0, murs1, 128);
  k_layer2<<<dim3(256, 16), 256, 0, stream>>>(y, murs1, w1, b1, stats + 8192);
  k_finalize<<<1, 256, 0, stream>>>(stats + 8192, ga1, be1, murs2, 128);
  k_layer3<<<dim3(256, 16, 2), 256, 0, stream>>>(y, murs2, w2, b2, ymaxb, yminb, stats + 16384);
  k_finalize<<<1, 256, 0, stream>>>(stats + 16384, ga2, be2, murs3, 256);
  k_final<<<dim3(32, 8, 16), dim3(32, 8), 0, stream>>>(ymaxb, yminb, murs3, out_feat);
}

// Round 4
// 1210.906 us; speedup vs baseline: 1.9769x; 1.2761x over previous
//
#include <hip/hip_runtime.h>

#define B_ 16
#define N_ 4096
#define S_ 1024
#define K_ 32
#define PITCH2 136   // 128 + 8 shorts: b128 frag reads -> 2-way bank alias (free)
#define PITCH1 168   // 160 + 8 shorts

typedef unsigned long long u64;
typedef short bf16x8 __attribute__((ext_vector_type(8)));   // 8 bf16 = 4 VGPR (guide §3)
typedef float f32x4 __attribute__((ext_vector_type(4)));

__device__ __forceinline__ unsigned short f2bf(float f) {
  unsigned u = __float_as_uint(f);
  unsigned r = (u + 0x7FFFu + ((u >> 16) & 1u)) >> 16;
  return (unsigned short)r;
}
__device__ __forceinline__ float bf2f(unsigned short h) {
  return __uint_as_float(((unsigned)h) << 16);
}

// DPP wave64 max reduce step: lane i takes max with lane (i - offset) pattern.
// After shr1,2,4,8 + bcast15 + bcast31, lane 63 holds the full-wave max.
#define DPP_MAX(v, ctrl)                                                        \
  {                                                                             \
    int _t = __builtin_amdgcn_update_dpp(__float_as_int(v), __float_as_int(v),  \
                                         ctrl, 0xf, 0xf, false);                \
    v = fmaxf(v, __int_as_float(_t));                                           \
  }

// ------- init: zero stats, pre-convert weights to bf16 [n][k] layouts -------
// wbf0: 128 x 160 (k-permuted: feat->0..127, xyz->128..130, pad->159)
// wbf1: 128 x 128 (native), wbf2: 256 x 128 (native)
__global__ void k_init(const float* __restrict__ w0, const float* __restrict__ w1,
                       const float* __restrict__ w2, unsigned short* __restrict__ wbf0,
                       unsigned short* __restrict__ wbf1, unsigned short* __restrict__ wbf2,
                       float* __restrict__ stats) {
  int t = blockIdx.x * blockDim.x + threadIdx.x;
  int st = gridDim.x * blockDim.x;
  for (int i = t; i < 32768; i += st) stats[i] = 0.0f;
  for (int i = t; i < 128 * 160; i += st) {
    int n = i / 160, k = i - n * 160;
    float v = (k < 128) ? w0[n * 131 + 3 + k] : (k < 131) ? w0[n * 131 + k - 128] : 0.0f;
    wbf0[i] = f2bf(v);
  }
  for (int i = t; i < 128 * 128; i += st) wbf1[i] = f2bf(w1[i]);
  for (int i = t; i < 256 * 128; i += st) wbf2[i] = f2bf(w2[i]);
}

// ---------------- farthest point sampling ----------------
// 512 threads/batch, 8 pts/thread in registers. Distance math bit-exact vs
// numpy: ((dx*dx+dy*dy)+dz*dz), rn mul/add, no fma. One barrier/iter
// (double-buffered cross-wave keys). Wave argmax: DPP max -> readlane 63 ->
// ballot equality (lowest lane = lowest index on ties) -> readlane owner.
__global__ __launch_bounds__(512) void k_fps(const float* __restrict__ xyz,
                                             float* __restrict__ new_xyz) {
  __shared__ float sx[N_], sy[N_], sz[N_];
  __shared__ u64 swk[2][8];
  int b = blockIdx.x, t = threadIdx.x;
  const float* base = xyz + (size_t)b * N_ * 3;
  for (int i = t; i < N_; i += 512) {
    sx[i] = base[i * 3]; sy[i] = base[i * 3 + 1]; sz[i] = base[i * 3 + 2];
  }
  __syncthreads();
  float px[8], py[8], pz[8], pd[8];
  int i0 = t * 8;
  #pragma unroll
  for (int j = 0; j < 8; ++j) {
    px[j] = sx[i0 + j]; py[j] = sy[i0 + j]; pz[j] = sz[i0 + j];
    pd[j] = 1e10f;
  }
  if (t == 0) {
    size_t o = (size_t)b * S_ * 3;
    new_xyz[o] = sx[0]; new_xyz[o + 1] = sy[0]; new_xyz[o + 2] = sz[0];
  }
  int cur = 0;
  for (int it = 0; it < S_; ++it) {
    float cx = sx[cur], cy = sy[cur], cz = sz[cur];
    float bestv = -1.0f; int besti = 0;
    #pragma unroll
    for (int j = 0; j < 8; ++j) {
      float dx = px[j] - cx, dy = py[j] - cy, dz = pz[j] - cz;
      float d = __fadd_rn(__fadd_rn(__fmul_rn(dx, dx), __fmul_rn(dy, dy)), __fmul_rn(dz, dz));
      float dm = fminf(pd[j], d);
      pd[j] = dm;
      if (dm > bestv) { bestv = dm; besti = j; }
    }
    float v = bestv;
    DPP_MAX(v, 0x111);  // row_shr:1
    DPP_MAX(v, 0x112);  // row_shr:2
    DPP_MAX(v, 0x114);  // row_shr:4
    DPP_MAX(v, 0x118);  // row_shr:8
    DPP_MAX(v, 0x142);  // row_bcast:15
    DPP_MAX(v, 0x143);  // row_bcast:31
    float wmax = __int_as_float(__builtin_amdgcn_readlane(__float_as_int(v), 63));
    u64 mask = __ballot(bestv == wmax);
    int owner = __ffsll((long long)mask) - 1;
    int widx = __builtin_amdgcn_readlane(i0 + besti, owner);
    if ((t & 63) == 0)
      swk[it & 1][t >> 6] = ((u64)__float_as_uint(wmax) << 32) | (unsigned)(4095 - widx);
    __syncthreads();
    const u64* kk = swk[it & 1];
    u64 k0 = kk[0];
    #pragma unroll
    for (int w = 1; w < 8; ++w) if (kk[w] > k0) k0 = kk[w];
    cur = 4095 - (int)(unsigned)(k0 & 0xFFFFFFFFull);
    if (t == 0 && it + 1 < S_) {
      size_t o = ((size_t)b * S_ + it + 1) * 3;
      new_xyz[o] = sx[cur]; new_xyz[o + 1] = sy[cur]; new_xyz[o + 2] = sz[cur];
    }
  }
}

// ---------------- transpose features (B,C,N) f32 -> (B,N,C) bf16 ----------
__global__ __launch_bounds__(256) void k_transpose(const float* __restrict__ f,
                                                   unsigned short* __restrict__ ft) {
  __shared__ float tile[32][33];
  int b = blockIdx.z;
  int n0 = blockIdx.x * 32, c0 = blockIdx.y * 32;
  int tx = threadIdx.x, ty = threadIdx.y;
  #pragma unroll
  for (int j = 0; j < 32; j += 8)
    tile[ty + j][tx] = f[((size_t)b * 128 + c0 + ty + j) * N_ + n0 + tx];
  __syncthreads();
  #pragma unroll
  for (int j = 0; j < 32; j += 8)
    ft[((size_t)b * N_ + n0 + ty + j) * 128 + c0 + tx] = f2bf(tile[tx][ty + j]);
}

// ---------------- ball query (unchanged, bit-exact formula) ----------------
__global__ __launch_bounds__(256) void k_ballq(const float* __restrict__ xyz,
                                               const float* __restrict__ new_xyz,
                                               int* __restrict__ ball_idx) {
  int b = blockIdx.y;
  int s = blockIdx.x * 4 + (threadIdx.x >> 6);
  int lane = threadIdx.x & 63;
  const float* pb = xyz + (size_t)b * N_ * 3;
  size_t q = (size_t)b * S_ + s;
  float qx = new_xyz[q * 3], qy = new_xyz[q * 3 + 1], qz = new_xyz[q * 3 + 2];
  float sq = __fadd_rn(__fadd_rn(__fmul_rn(qx, qx), __fmul_rn(qy, qy)), __fmul_rn(qz, qz));
  int* out = ball_idx + q * K_;
  int total = 0;
  int first_idx = -1;
  for (int basei = 0; basei < N_; basei += 64) {
    int i = basei + lane;
    float fx = pb[i * 3], fy = pb[i * 3 + 1], fz = pb[i * 3 + 2];
    float dot = __fmul_rn(qx, fx);
    dot = __fadd_rn(dot, __fmul_rn(qy, fy));
    dot = __fadd_rn(dot, __fmul_rn(qz, fz));
    float sd = __fadd_rn(__fadd_rn(__fmul_rn(fx, fx), __fmul_rn(fy, fy)), __fmul_rn(fz, fz));
    float dist = __fadd_rn(__fadd_rn(__fmul_rn(-2.0f, dot), sq), sd);
    bool within = (dist <= 0.36f);
    u64 m = __ballot(within);
    if (first_idx < 0 && m) first_idx = basei + __ffsll((long long)m) - 1;
    if (within) {
      int pos = total + __popcll(m & ((1ull << lane) - 1ull));
      if (pos < K_) out[pos] = i;
    }
    total += (int)__popcll(m);
    if (total >= K_) break;
  }
  if (total < K_) {
    int k2 = total + lane;
    if (k2 < K_) out[k2] = first_idx;
  }
}

// ============ MFMA layer kernels ============
// Per block: M=128 rows (4 queries x 32 samples), N=128 cols, K in LDS.
// Wave w <-> query w (M-tiles 2w, 2w+1). A-frag: G[m][k0..k0+7] b128 read;
// B-frag: W[n][k0..k0+7] b128 read. D: col=lane&15, row=(lane>>4)*4+reg.

#define MFMA(a, b, c) __builtin_amdgcn_mfma_f32_16x16x32_bf16(a, b, c, 0, 0, 0)

// ---- layer 1: gather + matmul K=131(pad 160) -> 128, channel-permuted ----
__global__ __launch_bounds__(256) void k_layer1(
    const float* __restrict__ xyz, const float* __restrict__ new_xyz,
    const unsigned short* __restrict__ featT, const int* __restrict__ ball_idx,
    const unsigned short* __restrict__ wbf0, const float* __restrict__ b0,
    unsigned short* __restrict__ y, float* __restrict__ stats) {
  __shared__ __align__(16) unsigned short Wl[128 * PITCH1];
  __shared__ __align__(16) unsigned short Gl[128 * PITCH1];
  __shared__ float sbias[128];
  int bb = blockIdx.y, s0 = blockIdx.x * 4, t = threadIdx.x;
  {
    int n = t >> 1, h = t & 1;
    const uint4* wr = (const uint4*)(wbf0 + n * 160 + h * 80);
    uint4* wl = (uint4*)(Wl + n * PITCH1 + h * 80);
    #pragma unroll
    for (int i = 0; i < 10; ++i) wl[i] = wr[i];
    if (t < 128) sbias[t] = b0[t];
  }
  {
    int r = t >> 1, h = t & 1;
    int q = r >> 5, ks = r & 31;
    size_t qg = (size_t)bb * S_ + s0 + q;
    int p = ball_idx[qg * K_ + ks]; if (p < 0) p = 0;
    const uint4* fr = (const uint4*)(featT + ((size_t)bb * N_ + p) * 128 + h * 64);
    uint4* gr = (uint4*)(Gl + r * PITCH1 + h * 64);
    #pragma unroll
    for (int i = 0; i < 8; ++i) gr[i] = fr[i];   // straight bf16 copy (16B)
    if (h == 0) {
      const float* pp = xyz + ((size_t)bb * N_ + p) * 3;
      Gl[r * PITCH1 + 128] = f2bf(pp[0] - new_xyz[qg * 3]);
      Gl[r * PITCH1 + 129] = f2bf(pp[1] - new_xyz[qg * 3 + 1]);
      Gl[r * PITCH1 + 130] = f2bf(pp[2] - new_xyz[qg * 3 + 2]);
    } else {
      for (int k = 131; k < 160; ++k) Gl[r * PITCH1 + k] = 0;
    }
  }
  __syncthreads();
  int w = t >> 6, L = t & 63, lm = L & 15, lg = L >> 4;
  f32x4 acc[2][8];
  #pragma unroll
  for (int mi = 0; mi < 2; ++mi)
    #pragma unroll
    for (int nt = 0; nt < 8; ++nt) acc[mi][nt] = (f32x4){0.f, 0.f, 0.f, 0.f};
  for (int kt = 0; kt < 5; ++kt) {
    int ko = kt * 32 + lg * 8;
    bf16x8 a0 = *(const bf16x8*)&Gl[(w * 32 + lm) * PITCH1 + ko];
    bf16x8 a1 = *(const bf16x8*)&Gl[(w * 32 + 16 + lm) * PITCH1 + ko];
    bf16x8 bv[8];
    #pragma unroll
    for (int nt = 0; nt < 8; ++nt)
      bv[nt] = *(const bf16x8*)&Wl[(nt * 16 + lm) * PITCH1 + ko];
    #pragma unroll
    for (int nt = 0; nt < 8; ++nt) {
      acc[0][nt] = MFMA(a0, bv[nt], acc[0][nt]);
      acc[1][nt] = MFMA(a1, bv[nt], acc[1][nt]);
    }
  }
  size_t qg = (size_t)bb * S_ + s0 + w;
  int slot = blockIdx.x & 31;
  #pragma unroll
  for (int nt = 0; nt < 8; ++nt) {
    int col = nt * 16 + lm;
    float bo = sbias[col];
    float s1 = 0.f, s2 = 0.f;
    #pragma unroll
    for (int mi = 0; mi < 2; ++mi)
      #pragma unroll
      for (int r = 0; r < 4; ++r) {
        float yv = acc[mi][nt][r] + bo;
        s1 += yv; s2 += yv * yv;
        int ks = mi * 16 + lg * 4 + r;
        y[(qg * K_ + ks) * 128 + col] = f2bf(yv);
      }
    s1 += __shfl_xor(s1, 16); s2 += __shfl_xor(s2, 16);
    s1 += __shfl_xor(s1, 32); s2 += __shfl_xor(s2, 32);
    if (lg == 0) {
      atomicAdd(stats + ((size_t)slot * 128 + col) * 2, s1);
      atomicAdd(stats + ((size_t)slot * 128 + col) * 2 + 1, s2);
    }
  }
}

// ---------------- finalize BN stats -> a=gamma*rsig, d=beta-a*mu ----------
__global__ void k_finalize(const float* __restrict__ stats, const float* __restrict__ gamma,
                           const float* __restrict__ beta, float* __restrict__ murs, int C) {
  for (int c = threadIdx.x; c < C; c += blockDim.x) {
    float s1 = 0.0f, s2 = 0.0f;
    for (int sl = 0; sl < 32; ++sl) {
      s1 += stats[((size_t)sl * C + c) * 2];
      s2 += stats[((size_t)sl * C + c) * 2 + 1];
    }
    const float inv = 1.0f / 524288.0f;  // 2^-19, exact
    float mu = s1 * inv;
    float var = s2 * inv - mu * mu;
    float a = gamma[c] * rsqrtf(var + 1e-5f);
    murs[c * 2] = a;
    murs[c * 2 + 1] = beta[c] - a * mu;
  }
}

// ---- layer 2: BN+relu(y) -> matmul 128->128, y overwritten IN-PLACE ----
__global__ __launch_bounds__(256) void k_layer2(
    unsigned short* y, const float* __restrict__ murs,
    const unsigned short* __restrict__ wbf1, const float* __restrict__ b1,
    float* __restrict__ stats) {
  __shared__ __align__(16) unsigned short Wl[128 * PITCH2];
  __shared__ __align__(16) unsigned short Gl[128 * PITCH2];
  __shared__ float sa[128], sd[128], sbias[128];
  int bb = blockIdx.y, s0 = blockIdx.x * 4, t = threadIdx.x;
  {
    int n = t >> 1, h = t & 1;
    const uint4* wr = (const uint4*)(wbf1 + n * 128 + h * 64);
    uint4* wl = (uint4*)(Wl + n * PITCH2 + h * 64);
    #pragma unroll
    for (int i = 0; i < 8; ++i) wl[i] = wr[i];
    if (t < 128) { sa[t] = murs[t * 2]; sd[t] = murs[t * 2 + 1]; sbias[t] = b1[t]; }
  }
  __syncthreads();
  {
    int r = t >> 1, h = t & 1;
    int q = r >> 5, ks = r & 31;
    size_t qg = (size_t)bb * S_ + s0 + q;
    const ushort4* yr = (const ushort4*)(y + (qg * K_ + ks) * 128 + h * 64);
    #pragma unroll
    for (int i = 0; i < 16; ++i) {
      ushort4 p = yr[i];
      int c = h * 64 + i * 4;
      ushort4 pk;
      pk.x = f2bf(fmaxf(sa[c]     * bf2f(p.x) + sd[c],     0.f));
      pk.y = f2bf(fmaxf(sa[c + 1] * bf2f(p.y) + sd[c + 1], 0.f));
      pk.z = f2bf(fmaxf(sa[c + 2] * bf2f(p.z) + sd[c + 2], 0.f));
      pk.w = f2bf(fmaxf(sa[c + 3] * bf2f(p.w) + sd[c + 3], 0.f));
      *(ushort4*)&Gl[r * PITCH2 + c] = pk;
    }
  }
  __syncthreads();
  int w = t >> 6, L = t & 63, lm = L & 15, lg = L >> 4;
  f32x4 acc[2][8];
  #pragma unroll
  for (int mi = 0; mi < 2; ++mi)
    #pragma unroll
    for (int nt = 0; nt < 8; ++nt) acc[mi][nt] = (f32x4){0.f, 0.f, 0.f, 0.f};
  for (int kt = 0; kt < 4; ++kt) {
    int ko = kt * 32 + lg * 8;
    bf16x8 a0 = *(const bf16x8*)&Gl[(w * 32 + lm) * PITCH2 + ko];
    bf16x8 a1 = *(const bf16x8*)&Gl[(w * 32 + 16 + lm) * PITCH2 + ko];
    bf16x8 bv[8];
    #pragma unroll
    for (int nt = 0; nt < 8; ++nt)
      bv[nt] = *(const bf16x8*)&Wl[(nt * 16 + lm) * PITCH2 + ko];
    #pragma unroll
    for (int nt = 0; nt < 8; ++nt) {
      acc[0][nt] = MFMA(a0, bv[nt], acc[0][nt]);
      acc[1][nt] = MFMA(a1, bv[nt], acc[1][nt]);
    }
  }
  size_t qg = (size_t)bb * S_ + s0 + w;
  int slot = blockIdx.x & 31;
  #pragma unroll
  for (int nt = 0; nt < 8; ++nt) {
    int col = nt * 16 + lm;
    float bo = sbias[col];
    float s1 = 0.f, s2 = 0.f;
    #pragma unroll
    for (int mi = 0; mi < 2; ++mi)
      #pragma unroll
      for (int r = 0; r < 4; ++r) {
        float yv = acc[mi][nt][r] + bo;
        s1 += yv; s2 += yv * yv;
        int ks = mi * 16 + lg * 4 + r;
        y[(qg * K_ + ks) * 128 + col] = f2bf(yv);
      }
    s1 += __shfl_xor(s1, 16); s2 += __shfl_xor(s2, 16);
    s1 += __shfl_xor(s1, 32); s2 += __shfl_xor(s2, 32);
    if (lg == 0) {
      atomicAdd(stats + ((size_t)slot * 128 + col) * 2, s1);
      atomicAdd(stats + ((size_t)slot * 128 + col) * 2 + 1, s2);
    }
  }
}

// ---- layer 3: BN+relu(y) -> matmul 128->256 (N split by blockIdx.z),
//      maxpool commutes with monotone BN+relu -> store ymax/ymin only ----
__global__ __launch_bounds__(256) void k_layer3(
    const unsigned short* __restrict__ y, const float* __restrict__ murs,
    const unsigned short* __restrict__ wbf2, const float* __restrict__ b2,
    unsigned short* __restrict__ ymax, unsigned short* __restrict__ ymin,
    float* __restrict__ stats) {
  __shared__ __align__(16) unsigned short Wl[128 * PITCH2];
  __shared__ __align__(16) unsigned short Gl[128 * PITCH2];
  __shared__ float sa[128], sd[128], sbias[128];
  int bb = blockIdx.y, s0 = blockIdx.x * 4, nh = blockIdx.z, t = threadIdx.x;
  {
    int n = t >> 1, h = t & 1;
    const uint4* wr = (const uint4*)(wbf2 + (size_t)(nh * 128 + n) * 128 + h * 64);
    uint4* wl = (uint4*)(Wl + n * PITCH2 + h * 64);
    #pragma unroll
    for (int i = 0; i < 8; ++i) wl[i] = wr[i];
    if (t < 128) { sa[t] = murs[t * 2]; sd[t] = murs[t * 2 + 1]; sbias[t] = b2[nh * 128 + t]; }
  }
  __syncthreads();
  {
    int r = t >> 1, h = t & 1;
    int q = r >> 5, ks = r & 31;
    size_t qg = (size_t)bb * S_ + s0 + q;
    const ushort4* yr = (const ushort4*)(y + (qg * K_ + ks) * 128 + h * 64);
    #pragma unroll
    for (int i = 0; i < 16; ++i) {
      ushort4 p = yr[i];
      int c = h * 64 + i * 4;
      ushort4 pk;
      pk.x = f2bf(fmaxf(sa[c]     * bf2f(p.x) + sd[c],     0.f));
      pk.y = f2bf(fmaxf(sa[c + 1] * bf2f(p.y) + sd[c + 1], 0.f));
      pk.z = f2bf(fmaxf(sa[c + 2] * bf2f(p.z) + sd[c + 2], 0.f));
      pk.w = f2bf(fmaxf(sa[c + 3] * bf2f(p.w) + sd[c + 3], 0.f));
      *(ushort4*)&Gl[r * PITCH2 + c] = pk;
    }
  }
  __syncthreads();
  int w = t >> 6, L = t & 63, lm = L & 15, lg = L >> 4;
  f32x4 acc[2][8];
  #pragma unroll
  for (int mi = 0; mi < 2; ++mi)
    #pragma unroll
    for (int nt = 0; nt < 8; ++nt) acc[mi][nt] = (f32x4){0.f, 0.f, 0.f, 0.f};
  for (int kt = 0; kt < 4; ++kt) {
    int ko = kt * 32 + lg * 8;
    bf16x8 a0 = *(const bf16x8*)&Gl[(w * 32 + lm) * PITCH2 + ko];
    bf16x8 a1 = *(const bf16x8*)&Gl[(w * 32 + 16 + lm) * PITCH2 + ko];
    bf16x8 bv[8];
    #pragma unroll
    for (int nt = 0; nt < 8; ++nt)
      bv[nt] = *(const bf16x8*)&Wl[(nt * 16 + lm) * PITCH2 + ko];
    #pragma unroll
    for (int nt = 0; nt < 8; ++nt) {
      acc[0][nt] = MFMA(a0, bv[nt], acc[0][nt]);
      acc[1][nt] = MFMA(a1, bv[nt], acc[1][nt]);
    }
  }
  size_t qg = (size_t)bb * S_ + s0 + w;
  int slot = blockIdx.x & 31;
  #pragma unroll
  for (int nt = 0; nt < 8; ++nt) {
    int col = nt * 16 + lm;
    int o = nh * 128 + col;
    float bo = sbias[col];
    float s1 = 0.f, s2 = 0.f, mx = -3.4e38f, mn = 3.4e38f;
    #pragma unroll
    for (int mi = 0; mi < 2; ++mi)
      #pragma unroll
      for (int r = 0; r < 4; ++r) {
        float yv = acc[mi][nt][r] + bo;
        s1 += yv; s2 += yv * yv;
        mx = fmaxf(mx, yv); mn = fminf(mn, yv);
      }
    s1 += __shfl_xor(s1, 16); s2 += __shfl_xor(s2, 16);
    s1 += __shfl_xor(s1, 32); s2 += __shfl_xor(s2, 32);
    mx = fmaxf(mx, __shfl_xor(mx, 16)); mx = fmaxf(mx, __shfl_xor(mx, 32));
    mn = fminf(mn, __shfl_xor(mn, 16)); mn = fminf(mn, __shfl_xor(mn, 32));
    if (lg == 0) {
      ymax[qg * 256 + o] = f2bf(mx);
      ymin[qg * 256 + o] = f2bf(mn);
      atomicAdd(stats + ((size_t)slot * 256 + o) * 2, s1);
      atomicAdd(stats + ((size_t)slot * 256 + o) * 2 + 1, s2);
    }
  }
}

// -------- final: select extreme by sign(a), BN+relu, transpose to (b,o,s) --
__global__ __launch_bounds__(256) void k_final(const unsigned short* __restrict__ ymax,
                                               const unsigned short* __restrict__ ymin,
                                               const float* __restrict__ murs,
                                               float* __restrict__ out2) {
  __shared__ float tile[32][33];
  int b = blockIdx.z, o0 = blockIdx.y * 32, s0 = blockIdx.x * 32;
  int tx = threadIdx.x, ty = threadIdx.y;
  float a_rd = murs[(o0 + tx) * 2];
  #pragma unroll
  for (int j = 0; j < 32; j += 8) {
    size_t src = ((size_t)b * S_ + s0 + ty + j) * 256 + o0 + tx;
    tile[ty + j][tx] = (a_rd >= 0.0f) ? bf2f(ymax[src]) : bf2f(ymin[src]);
  }
  __syncthreads();
  #pragma unroll
  for (int j = 0; j < 32; j += 8) {
    int o = o0 + ty + j;
    float a = murs[o * 2], dd = murs[o * 2 + 1];
    out2[((size_t)b * 256 + o) * S_ + s0 + tx] = fmaxf(a * tile[tx][ty + j] + dd, 0.0f);
  }
}

extern "C" void kernel_launch(void* const* d_in, const int* in_sizes, int n_in,
                              void* d_out, int out_size, void* d_ws, size_t ws_size,
                              hipStream_t stream) {
  (void)in_sizes; (void)n_in; (void)out_size; (void)ws_size;
  const float* xyz  = (const float*)d_in[0];
  const float* feat = (const float*)d_in[1];
  const float* w0   = (const float*)d_in[2];
  const float* b0   = (const float*)d_in[3];
  const float* ga0  = (const float*)d_in[4];
  const float* be0  = (const float*)d_in[5];
  const float* w1   = (const float*)d_in[6];
  const float* b1   = (const float*)d_in[7];
  const float* ga1  = (const float*)d_in[8];
  const float* be1  = (const float*)d_in[9];
  const float* w2   = (const float*)d_in[10];
  const float* b2   = (const float*)d_in[11];
  const float* ga2  = (const float*)d_in[12];
  const float* be2  = (const float*)d_in[13];

  float* out_xyz  = (float*)d_out;
  float* out_feat = out_xyz + (size_t)B_ * S_ * 3;

  char* ws = (char*)d_ws;
  size_t off = 0;
  auto alloc = [&](size_t bytes) -> void* {
    void* p = ws + off;
    off += (bytes + 255) & ~(size_t)255;
    return p;
  };
  // Total ~170 MB
  unsigned short* featT = (unsigned short*)alloc((size_t)B_ * N_ * 128 * 2);  // 16.8 MB bf16
  int*   ball  = (int*)alloc((size_t)B_ * S_ * K_ * 4);                       // 2.1 MB
  float* stats = (float*)alloc(32768 * 4);
  float* murs1 = (float*)alloc(128 * 2 * 4);
  float* murs2 = (float*)alloc(128 * 2 * 4);
  float* murs3 = (float*)alloc(256 * 2 * 4);
  unsigned short* wbf0 = (unsigned short*)alloc(128 * 160 * 2);
  unsigned short* wbf1 = (unsigned short*)alloc(128 * 128 * 2);
  unsigned short* wbf2 = (unsigned short*)alloc(256 * 128 * 2);
  unsigned short* ymaxb = (unsigned short*)alloc((size_t)B_ * S_ * 256 * 2);  // 8.4 MB
  unsigned short* yminb = (unsigned short*)alloc((size_t)B_ * S_ * 256 * 2);  // 8.4 MB
  unsigned short* y = (unsigned short*)alloc((size_t)B_ * S_ * K_ * 128 * 2); // 134 MB (y1 then y2 in-place)

  k_init<<<128, 256, 0, stream>>>(w0, w1, w2, wbf0, wbf1, wbf2, stats);
  k_fps<<<16, 512, 0, stream>>>(xyz, out_xyz);
  k_transpose<<<dim3(128, 4, 16), dim3(32, 8), 0, stream>>>(feat, featT);
  k_ballq<<<dim3(256, 16), 256, 0, stream>>>(xyz, out_xyz, ball);
  k_layer1<<<dim3(256, 16), 256, 0, stream>>>(xyz, out_xyz, featT, ball, wbf0, b0, y, stats);
  k_finalize<<<1, 256, 0, stream>>>(stats, ga0, be0, murs1, 128);
  k_layer2<<<dim3(256, 16), 256, 0, stream>>>(y, murs1, wbf1, b1, stats + 8192);
  k_finalize<<<1, 256, 0, stream>>>(stats + 8192, ga1, be1, murs2, 128);
  k_layer3<<<dim3(256, 16, 2), 256, 0, stream>>>(y, murs2, wbf2, b2, ymaxb, yminb, stats + 16384);
  k_finalize<<<1, 256, 0, stream>>>(stats + 16384, ga2, be2, murs3, 256);
  k_final<<<dim3(32, 8, 16), dim3(32, 8), 0, stream>>>(ymaxb, yminb, murs3, out_feat);
}

// Round 6
// 1206.849 us; speedup vs baseline: 1.9835x; 1.0034x over previous
//
#include <hip/hip_runtime.h>

#define B_ 16
#define N_ 4096
#define S_ 1024
#define K_ 32
#define PITCH2 136   // 128 + 8 shorts: b128 frag reads -> 2-way bank alias (free)
#define PITCH1 168   // 160 + 8 shorts

typedef unsigned long long u64;
typedef short bf16x8 __attribute__((ext_vector_type(8)));
typedef float f32x4 __attribute__((ext_vector_type(4)));
typedef float f32x2 __attribute__((ext_vector_type(2)));

__device__ __forceinline__ unsigned short f2bf(float f) {
  unsigned u = __float_as_uint(f);
  unsigned r = (u + 0x7FFFu + ((u >> 16) & 1u)) >> 16;
  return (unsigned short)r;
}
__device__ __forceinline__ float bf2f(unsigned short h) {
  return __uint_as_float(((unsigned)h) << 16);
}

// DPP wave64 max reduce: shr1,2,4,8 + bcast15 + bcast31 -> lane 63 = wave max
#define DPP_MAX(v, ctrl)                                                        \
  {                                                                             \
    int _t = __builtin_amdgcn_update_dpp(__float_as_int(v), __float_as_int(v),  \
                                         ctrl, 0xf, 0xf, false);                \
    v = fmaxf(v, __int_as_float(_t));                                           \
  }

// ===== fused front kernel: blocks 0-15 FPS | 16-31 init | 32+ transpose =====
// FPS (latency-bound serial chain, 16 CUs) runs while the other ~240 CUs do
// the independent weight-conversion and feature-transpose work.
__global__ __launch_bounds__(512) void k_front(
    const float* __restrict__ xyz, float* __restrict__ new_xyz,
    const float* __restrict__ feat, unsigned short* __restrict__ featT,
    const float* __restrict__ w0, const float* __restrict__ w1,
    const float* __restrict__ w2, unsigned short* __restrict__ wbf0,
    unsigned short* __restrict__ wbf1, unsigned short* __restrict__ wbf2,
    float* __restrict__ stats) {
  __shared__ __align__(16) float smem[N_ * 3 + 64];
  int blk = blockIdx.x, t = threadIdx.x;

  if (blk < 16) {
#pragma clang fp contract(off)
    // ---------------- farthest point sampling ----------------
    // 512 thr, 8 pts/thread (4 float2 pairs). Distance math bit-exact vs
    // numpy (((dx*dx+dy*dy)+dz*dz), rn, no contraction). One barrier/iter.
#if __has_builtin(__builtin_amdgcn_s_setprio)
    __builtin_amdgcn_s_setprio(3);
#endif
    float* sx = smem;
    float* sy = smem + N_;
    float* sz = smem + 2 * N_;
    u64* swk = (u64*)(smem + 3 * N_);   // [2][8]
    int b = blk;
    const float* base = xyz + (size_t)b * N_ * 3;
    for (int i = t; i < N_; i += 512) {
      sx[i] = base[i * 3]; sy[i] = base[i * 3 + 1]; sz[i] = base[i * 3 + 2];
    }
    __syncthreads();
    f32x2 px[4], py[4], pz[4], pd[4];
    int i0 = t * 8;
    #pragma unroll
    for (int j = 0; j < 4; ++j) {
      px[j] = (f32x2){sx[i0 + 2 * j], sx[i0 + 2 * j + 1]};
      py[j] = (f32x2){sy[i0 + 2 * j], sy[i0 + 2 * j + 1]};
      pz[j] = (f32x2){sz[i0 + 2 * j], sz[i0 + 2 * j + 1]};
      pd[j] = (f32x2){1e10f, 1e10f};
    }
    if (t == 0) {
      size_t o = (size_t)b * S_ * 3;
      new_xyz[o] = sx[0]; new_xyz[o + 1] = sy[0]; new_xyz[o + 2] = sz[0];
    }
    int cur = 0;
    for (int it = 0; it < S_; ++it) {
      float cx = sx[cur], cy = sy[cur], cz = sz[cur];
      f32x2 c2x = (f32x2){cx, cx}, c2y = (f32x2){cy, cy}, c2z = (f32x2){cz, cz};
      float bestv = -1.0f; int besti = 0;
      #pragma unroll
      for (int j = 0; j < 4; ++j) {
        f32x2 dx = px[j] - c2x;
        f32x2 dy = py[j] - c2y;
        f32x2 dz = pz[j] - c2z;
        f32x2 d = (dx * dx + dy * dy) + dz * dz;   // contract(off): exact rn chain
        f32x2 dm = __builtin_elementwise_min(pd[j], d);
        pd[j] = dm;
        if (dm.x > bestv) { bestv = dm.x; besti = 2 * j; }
        if (dm.y > bestv) { bestv = dm.y; besti = 2 * j + 1; }
      }
      float v = bestv;
      DPP_MAX(v, 0x111);  // row_shr:1
      DPP_MAX(v, 0x112);  // row_shr:2
      DPP_MAX(v, 0x114);  // row_shr:4
      DPP_MAX(v, 0x118);  // row_shr:8
      DPP_MAX(v, 0x142);  // row_bcast:15
      DPP_MAX(v, 0x143);  // row_bcast:31
      float wmax = __int_as_float(__builtin_amdgcn_readlane(__float_as_int(v), 63));
      u64 mask = __ballot(bestv == wmax);
      int owner = __ffsll((long long)mask) - 1;
      int widx = __builtin_amdgcn_readlane(i0 + besti, owner);
      if ((t & 63) == 0)
        swk[(it & 1) * 8 + (t >> 6)] =
            ((u64)__float_as_uint(wmax) << 32) | (unsigned)(4095 - widx);
      __syncthreads();
      const u64* kk = swk + (it & 1) * 8;
      u64 k0 = kk[0];
      #pragma unroll
      for (int w = 1; w < 8; ++w) if (kk[w] > k0) k0 = kk[w];
      cur = 4095 - (int)(unsigned)(k0 & 0xFFFFFFFFull);
      if (t == 0 && it + 1 < S_) {
        size_t o = ((size_t)b * S_ + it + 1) * 3;
        new_xyz[o] = sx[cur]; new_xyz[o + 1] = sy[cur]; new_xyz[o + 2] = sz[cur];
      }
    }
  } else if (blk < 32) {
    // ---------------- init: zero stats, weights -> bf16 [n][k] ----------------
    int id = (blk - 16) * 512 + t;
    const int st = 16 * 512;
    for (int i = id; i < 32768; i += st) stats[i] = 0.0f;
    for (int i = id; i < 128 * 160; i += st) {
      int n = i / 160, k = i - n * 160;
      float v = (k < 128) ? w0[n * 131 + 3 + k] : (k < 131) ? w0[n * 131 + k - 128] : 0.0f;
      wbf0[i] = f2bf(v);
    }
    for (int i = id; i < 128 * 128; i += st) wbf1[i] = f2bf(w1[i]);
    for (int i = id; i < 256 * 128; i += st) wbf2[i] = f2bf(w2[i]);
  } else {
    // ------------- transpose features (B,C,N) f32 -> (B,N,C) bf16 -------------
    float (*tile)[33] = (float(*)[33])smem;
    int blk2 = blk - 32;
    int n0 = (blk2 & 127) * 32;
    int c0 = ((blk2 >> 7) & 3) * 32;
    int b = blk2 >> 9;
    int tx = t & 31, ty = t >> 5;   // ty 0..15
    #pragma unroll
    for (int j = 0; j < 32; j += 16)
      tile[ty + j][tx] = feat[((size_t)b * 128 + c0 + ty + j) * N_ + n0 + tx];
    __syncthreads();
    #pragma unroll
    for (int j = 0; j < 32; j += 16)
      featT[((size_t)b * N_ + n0 + ty + j) * 128 + c0 + tx] = f2bf(tile[tx][ty + j]);
  }
}

// ---------------- ball query (unchanged, bit-exact formula) ----------------
__global__ __launch_bounds__(256) void k_ballq(const float* __restrict__ xyz,
                                               const float* __restrict__ new_xyz,
                                               int* __restrict__ ball_idx) {
  int b = blockIdx.y;
  int s = blockIdx.x * 4 + (threadIdx.x >> 6);
  int lane = threadIdx.x & 63;
  const float* pb = xyz + (size_t)b * N_ * 3;
  size_t q = (size_t)b * S_ + s;
  float qx = new_xyz[q * 3], qy = new_xyz[q * 3 + 1], qz = new_xyz[q * 3 + 2];
  float sq = __fadd_rn(__fadd_rn(__fmul_rn(qx, qx), __fmul_rn(qy, qy)), __fmul_rn(qz, qz));
  int* out = ball_idx + q * K_;
  int total = 0;
  int first_idx = -1;
  for (int basei = 0; basei < N_; basei += 64) {
    int i = basei + lane;
    float fx = pb[i * 3], fy = pb[i * 3 + 1], fz = pb[i * 3 + 2];
    float dot = __fmul_rn(qx, fx);
    dot = __fadd_rn(dot, __fmul_rn(qy, fy));
    dot = __fadd_rn(dot, __fmul_rn(qz, fz));
    float sd = __fadd_rn(__fadd_rn(__fmul_rn(fx, fx), __fmul_rn(fy, fy)), __fmul_rn(fz, fz));
    float dist = __fadd_rn(__fadd_rn(__fmul_rn(-2.0f, dot), sq), sd);
    bool within = (dist <= 0.36f);
    u64 m = __ballot(within);
    if (first_idx < 0 && m) first_idx = basei + __ffsll((long long)m) - 1;
    if (within) {
      int pos = total + __popcll(m & ((1ull << lane) - 1ull));
      if (pos < K_) out[pos] = i;
    }
    total += (int)__popcll(m);
    if (total >= K_) break;
  }
  if (total < K_) {
    int k2 = total + lane;
    if (k2 < K_) out[k2] = first_idx;
  }
}

// ============ MFMA layer kernels (unchanged from round 4) ============
#define MFMA(a, b, c) __builtin_amdgcn_mfma_f32_16x16x32_bf16(a, b, c, 0, 0, 0)

__global__ __launch_bounds__(256) void k_layer1(
    const float* __restrict__ xyz, const float* __restrict__ new_xyz,
    const unsigned short* __restrict__ featT, const int* __restrict__ ball_idx,
    const unsigned short* __restrict__ wbf0, const float* __restrict__ b0,
    unsigned short* __restrict__ y, float* __restrict__ stats) {
  __shared__ __align__(16) unsigned short Wl[128 * PITCH1];
  __shared__ __align__(16) unsigned short Gl[128 * PITCH1];
  __shared__ float sbias[128];
  int bb = blockIdx.y, s0 = blockIdx.x * 4, t = threadIdx.x;
  {
    int n = t >> 1, h = t & 1;
    const uint4* wr = (const uint4*)(wbf0 + n * 160 + h * 80);
    uint4* wl = (uint4*)(Wl + n * PITCH1 + h * 80);
    #pragma unroll
    for (int i = 0; i < 10; ++i) wl[i] = wr[i];
    if (t < 128) sbias[t] = b0[t];
  }
  {
    int r = t >> 1, h = t & 1;
    int q = r >> 5, ks = r & 31;
    size_t qg = (size_t)bb * S_ + s0 + q;
    int p = ball_idx[qg * K_ + ks]; if (p < 0) p = 0;
    const uint4* fr = (const uint4*)(featT + ((size_t)bb * N_ + p) * 128 + h * 64);
    uint4* gr = (uint4*)(Gl + r * PITCH1 + h * 64);
    #pragma unroll
    for (int i = 0; i < 8; ++i) gr[i] = fr[i];
    if (h == 0) {
      const float* pp = xyz + ((size_t)bb * N_ + p) * 3;
      Gl[r * PITCH1 + 128] = f2bf(pp[0] - new_xyz[qg * 3]);
      Gl[r * PITCH1 + 129] = f2bf(pp[1] - new_xyz[qg * 3 + 1]);
      Gl[r * PITCH1 + 130] = f2bf(pp[2] - new_xyz[qg * 3 + 2]);
    } else {
      for (int k = 131; k < 160; ++k) Gl[r * PITCH1 + k] = 0;
    }
  }
  __syncthreads();
  int w = t >> 6, L = t & 63, lm = L & 15, lg = L >> 4;
  f32x4 acc[2][8];
  #pragma unroll
  for (int mi = 0; mi < 2; ++mi)
    #pragma unroll
    for (int nt = 0; nt < 8; ++nt) acc[mi][nt] = (f32x4){0.f, 0.f, 0.f, 0.f};
  for (int kt = 0; kt < 5; ++kt) {
    int ko = kt * 32 + lg * 8;
    bf16x8 a0 = *(const bf16x8*)&Gl[(w * 32 + lm) * PITCH1 + ko];
    bf16x8 a1 = *(const bf16x8*)&Gl[(w * 32 + 16 + lm) * PITCH1 + ko];
    bf16x8 bv[8];
    #pragma unroll
    for (int nt = 0; nt < 8; ++nt)
      bv[nt] = *(const bf16x8*)&Wl[(nt * 16 + lm) * PITCH1 + ko];
    #pragma unroll
    for (int nt = 0; nt < 8; ++nt) {
      acc[0][nt] = MFMA(a0, bv[nt], acc[0][nt]);
      acc[1][nt] = MFMA(a1, bv[nt], acc[1][nt]);
    }
  }
  size_t qg = (size_t)bb * S_ + s0 + w;
  int slot = blockIdx.x & 31;
  #pragma unroll
  for (int nt = 0; nt < 8; ++nt) {
    int col = nt * 16 + lm;
    float bo = sbias[col];
    float s1 = 0.f, s2 = 0.f;
    #pragma unroll
    for (int mi = 0; mi < 2; ++mi)
      #pragma unroll
      for (int r = 0; r < 4; ++r) {
        float yv = acc[mi][nt][r] + bo;
        s1 += yv; s2 += yv * yv;
        int ks = mi * 16 + lg * 4 + r;
        y[(qg * K_ + ks) * 128 + col] = f2bf(yv);
      }
    s1 += __shfl_xor(s1, 16); s2 += __shfl_xor(s2, 16);
    s1 += __shfl_xor(s1, 32); s2 += __shfl_xor(s2, 32);
    if (lg == 0) {
      atomicAdd(stats + ((size_t)slot * 128 + col) * 2, s1);
      atomicAdd(stats + ((size_t)slot * 128 + col) * 2 + 1, s2);
    }
  }
}

__global__ void k_finalize(const float* __restrict__ stats, const float* __restrict__ gamma,
                           const float* __restrict__ beta, float* __restrict__ murs, int C) {
  for (int c = threadIdx.x; c < C; c += blockDim.x) {
    float s1 = 0.0f, s2 = 0.0f;
    for (int sl = 0; sl < 32; ++sl) {
      s1 += stats[((size_t)sl * C + c) * 2];
      s2 += stats[((size_t)sl * C + c) * 2 + 1];
    }
    const float inv = 1.0f / 524288.0f;  // 2^-19, exact
    float mu = s1 * inv;
    float var = s2 * inv - mu * mu;
    float a = gamma[c] * rsqrtf(var + 1e-5f);
    murs[c * 2] = a;
    murs[c * 2 + 1] = beta[c] - a * mu;
  }
}

__global__ __launch_bounds__(256) void k_layer2(
    unsigned short* y, const float* __restrict__ murs,
    const unsigned short* __restrict__ wbf1, const float* __restrict__ b1,
    float* __restrict__ stats) {
  __shared__ __align__(16) unsigned short Wl[128 * PITCH2];
  __shared__ __align__(16) unsigned short Gl[128 * PITCH2];
  __shared__ float sa[128], sd[128], sbias[128];
  int bb = blockIdx.y, s0 = blockIdx.x * 4, t = threadIdx.x;
  {
    int n = t >> 1, h = t & 1;
    const uint4* wr = (const uint4*)(wbf1 + n * 128 + h * 64);
    uint4* wl = (uint4*)(Wl + n * PITCH2 + h * 64);
    #pragma unroll
    for (int i = 0; i < 8; ++i) wl[i] = wr[i];
    if (t < 128) { sa[t] = murs[t * 2]; sd[t] = murs[t * 2 + 1]; sbias[t] = b1[t]; }
  }
  __syncthreads();
  {
    int r = t >> 1, h = t & 1;
    int q = r >> 5, ks = r & 31;
    size_t qg = (size_t)bb * S_ + s0 + q;
    const ushort4* yr = (const ushort4*)(y + (qg * K_ + ks) * 128 + h * 64);
    #pragma unroll
    for (int i = 0; i < 16; ++i) {
      ushort4 p = yr[i];
      int c = h * 64 + i * 4;
      ushort4 pk;
      pk.x = f2bf(fmaxf(sa[c]     * bf2f(p.x) + sd[c],     0.f));
      pk.y = f2bf(fmaxf(sa[c + 1] * bf2f(p.y) + sd[c + 1], 0.f));
      pk.z = f2bf(fmaxf(sa[c + 2] * bf2f(p.z) + sd[c + 2], 0.f));
      pk.w = f2bf(fmaxf(sa[c + 3] * bf2f(p.w) + sd[c + 3], 0.f));
      *(ushort4*)&Gl[r * PITCH2 + c] = pk;
    }
  }
  __syncthreads();
  int w = t >> 6, L = t & 63, lm = L & 15, lg = L >> 4;
  f32x4 acc[2][8];
  #pragma unroll
  for (int mi = 0; mi < 2; ++mi)
    #pragma unroll
    for (int nt = 0; nt < 8; ++nt) acc[mi][nt] = (f32x4){0.f, 0.f, 0.f, 0.f};
  for (int kt = 0; kt < 4; ++kt) {
    int ko = kt * 32 + lg * 8;
    bf16x8 a0 = *(const bf16x8*)&Gl[(w * 32 + lm) * PITCH2 + ko];
    bf16x8 a1 = *(const bf16x8*)&Gl[(w * 32 + 16 + lm) * PITCH2 + ko];
    bf16x8 bv[8];
    #pragma unroll
    for (int nt = 0; nt < 8; ++nt)
      bv[nt] = *(const bf16x8*)&Wl[(nt * 16 + lm) * PITCH2 + ko];
    #pragma unroll
    for (int nt = 0; nt < 8; ++nt) {
      acc[0][nt] = MFMA(a0, bv[nt], acc[0][nt]);
      acc[1][nt] = MFMA(a1, bv[nt], acc[1][nt]);
    }
  }
  size_t qg = (size_t)bb * S_ + s0 + w;
  int slot = blockIdx.x & 31;
  #pragma unroll
  for (int nt = 0; nt < 8; ++nt) {
    int col = nt * 16 + lm;
    float bo = sbias[col];
    float s1 = 0.f, s2 = 0.f;
    #pragma unroll
    for (int mi = 0; mi < 2; ++mi)
      #pragma unroll
      for (int r = 0; r < 4; ++r) {
        float yv = acc[mi][nt][r] + bo;
        s1 += yv; s2 += yv * yv;
        int ks = mi * 16 + lg * 4 + r;
        y[(qg * K_ + ks) * 128 + col] = f2bf(yv);
      }
    s1 += __shfl_xor(s1, 16); s2 += __shfl_xor(s2, 16);
    s1 += __shfl_xor(s1, 32); s2 += __shfl_xor(s2, 32);
    if (lg == 0) {
      atomicAdd(stats + ((size_t)slot * 128 + col) * 2, s1);
      atomicAdd(stats + ((size_t)slot * 128 + col) * 2 + 1, s2);
    }
  }
}

__global__ __launch_bounds__(256) void k_layer3(
    const unsigned short* __restrict__ y, const float* __restrict__ murs,
    const unsigned short* __restrict__ wbf2, const float* __restrict__ b2,
    unsigned short* __restrict__ ymax, unsigned short* __restrict__ ymin,
    float* __restrict__ stats) {
  __shared__ __align__(16) unsigned short Wl[128 * PITCH2];
  __shared__ __align__(16) unsigned short Gl[128 * PITCH2];
  __shared__ float sa[128], sd[128], sbias[128];
  int bb = blockIdx.y, s0 = blockIdx.x * 4, nh = blockIdx.z, t = threadIdx.x;
  {
    int n = t >> 1, h = t & 1;
    const uint4* wr = (const uint4*)(wbf2 + (size_t)(nh * 128 + n) * 128 + h * 64);
    uint4* wl = (uint4*)(Wl + n * PITCH2 + h * 64);
    #pragma unroll
    for (int i = 0; i < 8; ++i) wl[i] = wr[i];
    if (t < 128) { sa[t] = murs[t * 2]; sd[t] = murs[t * 2 + 1]; sbias[t] = b2[nh * 128 + t]; }
  }
  __syncthreads();
  {
    int r = t >> 1, h = t & 1;
    int q = r >> 5, ks = r & 31;
    size_t qg = (size_t)bb * S_ + s0 + q;
    const ushort4* yr = (const ushort4*)(y + (qg * K_ + ks) * 128 + h * 64);
    #pragma unroll
    for (int i = 0; i < 16; ++i) {
      ushort4 p = yr[i];
      int c = h * 64 + i * 4;
      ushort4 pk;
      pk.x = f2bf(fmaxf(sa[c]     * bf2f(p.x) + sd[c],     0.f));
      pk.y = f2bf(fmaxf(sa[c + 1] * bf2f(p.y) + sd[c + 1], 0.f));
      pk.z = f2bf(fmaxf(sa[c + 2] * bf2f(p.z) + sd[c + 2], 0.f));
      pk.w = f2bf(fmaxf(sa[c + 3] * bf2f(p.w) + sd[c + 3], 0.f));
      *(ushort4*)&Gl[r * PITCH2 + c] = pk;
    }
  }
  __syncthreads();
  int w = t >> 6, L = t & 63, lm = L & 15, lg = L >> 4;
  f32x4 acc[2][8];
  #pragma unroll
  for (int mi = 0; mi < 2; ++mi)
    #pragma unroll
    for (int nt = 0; nt < 8; ++nt) acc[mi][nt] = (f32x4){0.f, 0.f, 0.f, 0.f};
  for (int kt = 0; kt < 4; ++kt) {
    int ko = kt * 32 + lg * 8;
    bf16x8 a0 = *(const bf16x8*)&Gl[(w * 32 + lm) * PITCH2 + ko];
    bf16x8 a1 = *(const bf16x8*)&Gl[(w * 32 + 16 + lm) * PITCH2 + ko];
    bf16x8 bv[8];
    #pragma unroll
    for (int nt = 0; nt < 8; ++nt)
      bv[nt] = *(const bf16x8*)&Wl[(nt * 16 + lm) * PITCH2 + ko];
    #pragma unroll
    for (int nt = 0; nt < 8; ++nt) {
      acc[0][nt] = MFMA(a0, bv[nt], acc[0][nt]);
      acc[1][nt] = MFMA(a1, bv[nt], acc[1][nt]);
    }
  }
  size_t qg = (size_t)bb * S_ + s0 + w;
  int slot = blockIdx.x & 31;
  #pragma unroll
  for (int nt = 0; nt < 8; ++nt) {
    int col = nt * 16 + lm;
    int o = nh * 128 + col;
    float bo = sbias[col];
    float s1 = 0.f, s2 = 0.f, mx = -3.4e38f, mn = 3.4e38f;
    #pragma unroll
    for (int mi = 0; mi < 2; ++mi)
      #pragma unroll
      for (int r = 0; r < 4; ++r) {
        float yv = acc[mi][nt][r] + bo;
        s1 += yv; s2 += yv * yv;
        mx = fmaxf(mx, yv); mn = fminf(mn, yv);
      }
    s1 += __shfl_xor(s1, 16); s2 += __shfl_xor(s2, 16);
    s1 += __shfl_xor(s1, 32); s2 += __shfl_xor(s2, 32);
    mx = fmaxf(mx, __shfl_xor(mx, 16)); mx = fmaxf(mx, __shfl_xor(mx, 32));
    mn = fminf(mn, __shfl_xor(mn, 16)); mn = fminf(mn, __shfl_xor(mn, 32));
    if (lg == 0) {
      ymax[qg * 256 + o] = f2bf(mx);
      ymin[qg * 256 + o] = f2bf(mn);
      atomicAdd(stats + ((size_t)slot * 256 + o) * 2, s1);
      atomicAdd(stats + ((size_t)slot * 256 + o) * 2 + 1, s2);
    }
  }
}

__global__ __launch_bounds__(256) void k_final(const unsigned short* __restrict__ ymax,
                                               const unsigned short* __restrict__ ymin,
                                               const float* __restrict__ murs,
                                               float* __restrict__ out2) {
  __shared__ float tile[32][33];
  int b = blockIdx.z, o0 = blockIdx.y * 32, s0 = blockIdx.x * 32;
  int tx = threadIdx.x, ty = threadIdx.y;
  float a_rd = murs[(o0 + tx) * 2];
  #pragma unroll
  for (int j = 0; j < 32; j += 8) {
    size_t src = ((size_t)b * S_ + s0 + ty + j) * 256 + o0 + tx;
    tile[ty + j][tx] = (a_rd >= 0.0f) ? bf2f(ymax[src]) : bf2f(ymin[src]);
  }
  __syncthreads();
  #pragma unroll
  for (int j = 0; j < 32; j += 8) {
    int o = o0 + ty + j;
    float a = murs[o * 2], dd = murs[o * 2 + 1];
    out2[((size_t)b * 256 + o) * S_ + s0 + tx] = fmaxf(a * tile[tx][ty + j] + dd, 0.0f);
  }
}

extern "C" void kernel_launch(void* const* d_in, const int* in_sizes, int n_in,
                              void* d_out, int out_size, void* d_ws, size_t ws_size,
                              hipStream_t stream) {
  (void)in_sizes; (void)n_in; (void)out_size; (void)ws_size;
  const float* xyz  = (const float*)d_in[0];
  const float* feat = (const float*)d_in[1];
  const float* w0   = (const float*)d_in[2];
  const float* b0   = (const float*)d_in[3];
  const float* ga0  = (const float*)d_in[4];
  const float* be0  = (const float*)d_in[5];
  const float* w1   = (const float*)d_in[6];
  const float* b1   = (const float*)d_in[7];
  const float* ga1  = (const float*)d_in[8];
  const float* be1  = (const float*)d_in[9];
  const float* w2   = (const float*)d_in[10];
  const float* b2   = (const float*)d_in[11];
  const float* ga2  = (const float*)d_in[12];
  const float* be2  = (const float*)d_in[13];

  float* out_xyz  = (float*)d_out;
  float* out_feat = out_xyz + (size_t)B_ * S_ * 3;

  char* ws = (char*)d_ws;
  size_t off = 0;
  auto alloc = [&](size_t bytes) -> void* {
    void* p = ws + off;
    off += (bytes + 255) & ~(size_t)255;
    return p;
  };
  // Total ~170 MB
  unsigned short* featT = (unsigned short*)alloc((size_t)B_ * N_ * 128 * 2);  // 16.8 MB bf16
  int*   ball  = (int*)alloc((size_t)B_ * S_ * K_ * 4);                       // 2.1 MB
  float* stats = (float*)alloc(32768 * 4);
  float* murs1 = (float*)alloc(128 * 2 * 4);
  float* murs2 = (float*)alloc(128 * 2 * 4);
  float* murs3 = (float*)alloc(256 * 2 * 4);
  unsigned short* wbf0 = (unsigned short*)alloc(128 * 160 * 2);
  unsigned short* wbf1 = (unsigned short*)alloc(128 * 128 * 2);
  unsigned short* wbf2 = (unsigned short*)alloc(256 * 128 * 2);
  unsigned short* ymaxb = (unsigned short*)alloc((size_t)B_ * S_ * 256 * 2);  // 8.4 MB
  unsigned short* yminb = (unsigned short*)alloc((size_t)B_ * S_ * 256 * 2);  // 8.4 MB
  unsigned short* y = (unsigned short*)alloc((size_t)B_ * S_ * K_ * 128 * 2); // 134 MB (y1 then y2 in-place)

  // blocks: 16 fps | 16 init | 8192 transpose
  k_front<<<16 + 16 + 8192, 512, 0, stream>>>(xyz, out_xyz, feat, featT,
                                              w0, w1, w2, wbf0, wbf1, wbf2, stats);
  k_ballq<<<dim3(256, 16), 256, 0, stream>>>(xyz, out_xyz, ball);
  k_layer1<<<dim3(256, 16), 256, 0, stream>>>(xyz, out_xyz, featT, ball, wbf0, b0, y, stats);
  k_finalize<<<1, 256, 0, stream>>>(stats, ga0, be0, murs1, 128);
  k_layer2<<<dim3(256, 16), 256, 0, stream>>>(y, murs1, wbf1, b1, stats + 8192);
  k_finalize<<<1, 256, 0, stream>>>(stats + 8192, ga1, be1, murs2, 128);
  k_layer3<<<dim3(256, 16, 2), 256, 0, stream>>>(y, murs2, wbf2, b2, ymaxb, yminb, stats + 16384);
  k_finalize<<<1, 256, 0, stream>>>(stats + 16384, ga2, be2, murs3, 256);
  k_final<<<dim3(32, 8, 16), dim3(32, 8), 0, stream>>>(ymaxb, yminb, murs3, out_feat);
}

// Round 7
// 1171.604 us; speedup vs baseline: 2.0432x; 1.0301x over previous
//
#include <hip/hip_runtime.h>

#define B_ 16
#define N_ 4096
#define S_ 1024
#define K_ 32
#define PITCH2 136   // 128 + 8 shorts: b128 frag reads -> 2-way bank alias (free)
#define PITCH1 168   // 160 + 8 shorts

typedef unsigned long long u64;
typedef short bf16x8 __attribute__((ext_vector_type(8)));
typedef float f32x4 __attribute__((ext_vector_type(4)));
typedef float f32x2 __attribute__((ext_vector_type(2)));

__device__ __forceinline__ unsigned short f2bf(float f) {
  unsigned u = __float_as_uint(f);
  unsigned r = (u + 0x7FFFu + ((u >> 16) & 1u)) >> 16;
  return (unsigned short)r;
}
__device__ __forceinline__ float bf2f(unsigned short h) {
  return __uint_as_float(((unsigned)h) << 16);
}

// DPP wave64 max reduce: shr1,2,4,8 + bcast15 + bcast31 -> lane 63 = wave max
#define DPP_MAX(v, ctrl)                                                        \
  {                                                                             \
    int _t = __builtin_amdgcn_update_dpp(__float_as_int(v), __float_as_int(v),  \
                                         ctrl, 0xf, 0xf, false);                \
    v = fmaxf(v, __int_as_float(_t));                                           \
  }

// ===== fused front kernel: blocks 0-15 FPS | 16-31 init | 32+ transpose =====
// FPS (latency-bound serial chain, 16 CUs) runs while the other ~240 CUs do
// the independent weight-conversion and feature-transpose work.
// KEY FIX (r7): no global stores inside the FPS loop. __syncthreads drains
// vmcnt(0) (guide §5/m97), so a per-iter global store made every barrier wait
// for HBM store-ack (~hundreds of cyc) -- the dominant serial term r3-r6.
// Selected indices go to LDS; new_xyz is written after the loop.
__global__ __launch_bounds__(512) void k_front(
    const float* __restrict__ xyz, float* __restrict__ new_xyz,
    const float* __restrict__ feat, unsigned short* __restrict__ featT,
    const float* __restrict__ w0, const float* __restrict__ w1,
    const float* __restrict__ w2, unsigned short* __restrict__ wbf0,
    unsigned short* __restrict__ wbf1, unsigned short* __restrict__ wbf2,
    float* __restrict__ stats) {
  __shared__ __align__(16) float smem[N_ * 4 + S_ + 64];  // 64KB pts + 4KB idxs + keys
  int blk = blockIdx.x, t = threadIdx.x;

  if (blk < 16) {
#pragma clang fp contract(off)
    // ---------------- farthest point sampling ----------------
    // 512 thr, 8 pts/thread. Distance math bit-exact vs numpy
    // (((dx*dx+dy*dy)+dz*dz), rn, no contraction). One barrier/iter.
#if __has_builtin(__builtin_amdgcn_s_setprio)
    __builtin_amdgcn_s_setprio(3);
#endif
    float4* pts = (float4*)smem;              // [4096] xyz_ as float4
    int* idxs = (int*)(smem + N_ * 4);        // [1024] selected indices
    u64* swk = (u64*)(smem + N_ * 4 + S_);    // [2][8] cross-wave keys
    int b = blk;
    const float* base = xyz + (size_t)b * N_ * 3;
    for (int i = t; i < N_; i += 512)
      pts[i] = make_float4(base[i * 3], base[i * 3 + 1], base[i * 3 + 2], 0.0f);
    if (t == 0) idxs[0] = 0;
    __syncthreads();
    f32x2 px[4], py[4], pz[4], pd[4];
    int i0 = t * 8;
    #pragma unroll
    for (int j = 0; j < 4; ++j) {
      float4 p0 = pts[i0 + 2 * j], p1 = pts[i0 + 2 * j + 1];
      px[j] = (f32x2){p0.x, p1.x};
      py[j] = (f32x2){p0.y, p1.y};
      pz[j] = (f32x2){p0.z, p1.z};
      pd[j] = (f32x2){1e10f, 1e10f};
    }
    int cur = 0;
    for (int it = 0; it < S_; ++it) {
      float4 c = pts[cur];                    // single ds_read_b128
      f32x2 c2x = (f32x2){c.x, c.x}, c2y = (f32x2){c.y, c.y}, c2z = (f32x2){c.z, c.z};
      float bestv = -1.0f; int besti = 0;
      #pragma unroll
      for (int j = 0; j < 4; ++j) {
        f32x2 dx = px[j] - c2x;
        f32x2 dy = py[j] - c2y;
        f32x2 dz = pz[j] - c2z;
        f32x2 d = (dx * dx + dy * dy) + dz * dz;   // contract(off): exact rn chain
        f32x2 dm = __builtin_elementwise_min(pd[j], d);
        pd[j] = dm;
        if (dm.x > bestv) { bestv = dm.x; besti = 2 * j; }
        if (dm.y > bestv) { bestv = dm.y; besti = 2 * j + 1; }
      }
      float v = bestv;
      DPP_MAX(v, 0x111);  // row_shr:1
      DPP_MAX(v, 0x112);  // row_shr:2
      DPP_MAX(v, 0x114);  // row_shr:4
      DPP_MAX(v, 0x118);  // row_shr:8
      DPP_MAX(v, 0x142);  // row_bcast:15
      DPP_MAX(v, 0x143);  // row_bcast:31
      float wmax = __int_as_float(__builtin_amdgcn_readlane(__float_as_int(v), 63));
      u64 mask = __ballot(bestv == wmax);
      int owner = __ffsll((long long)mask) - 1;
      int widx = __builtin_amdgcn_readlane(i0 + besti, owner);
      if ((t & 63) == 0)
        swk[(it & 1) * 8 + (t >> 6)] =
            ((u64)__float_as_uint(wmax) << 32) | (unsigned)(4095 - widx);
      __syncthreads();
      const u64* kk = swk + (it & 1) * 8;
      u64 k0 = kk[0];
      #pragma unroll
      for (int w = 1; w < 8; ++w) if (kk[w] > k0) k0 = kk[w];
      cur = 4095 - (int)(unsigned)(k0 & 0xFFFFFFFFull);
      if (t == 0 && it + 1 < S_) idxs[it + 1] = cur;   // LDS only -- cheap drain
    }
    __syncthreads();
    // write new_xyz once, outside the serial loop
    for (int i = t; i < S_; i += 512) {
      float4 v = pts[idxs[i]];
      size_t o = ((size_t)b * S_ + i) * 3;
      new_xyz[o] = v.x; new_xyz[o + 1] = v.y; new_xyz[o + 2] = v.z;
    }
  } else if (blk < 32) {
    // ---------------- init: zero stats, weights -> bf16 [n][k] ----------------
    int id = (blk - 16) * 512 + t;
    const int st = 16 * 512;
    for (int i = id; i < 32768; i += st) stats[i] = 0.0f;
    for (int i = id; i < 128 * 160; i += st) {
      int n = i / 160, k = i - n * 160;
      float v = (k < 128) ? w0[n * 131 + 3 + k] : (k < 131) ? w0[n * 131 + k - 128] : 0.0f;
      wbf0[i] = f2bf(v);
    }
    for (int i = id; i < 128 * 128; i += st) wbf1[i] = f2bf(w1[i]);
    for (int i = id; i < 256 * 128; i += st) wbf2[i] = f2bf(w2[i]);
  } else {
    // ------------- transpose features (B,C,N) f32 -> (B,N,C) bf16 -------------
    float (*tile)[33] = (float(*)[33])smem;
    int blk2 = blk - 32;
    int n0 = (blk2 & 127) * 32;
    int c0 = ((blk2 >> 7) & 3) * 32;
    int b = blk2 >> 9;
    int tx = t & 31, ty = t >> 5;   // ty 0..15
    #pragma unroll
    for (int j = 0; j < 32; j += 16)
      tile[ty + j][tx] = feat[((size_t)b * 128 + c0 + ty + j) * N_ + n0 + tx];
    __syncthreads();
    #pragma unroll
    for (int j = 0; j < 32; j += 16)
      featT[((size_t)b * N_ + n0 + ty + j) * 128 + c0 + tx] = f2bf(tile[tx][ty + j]);
  }
}

// ---------------- ball query (unchanged, bit-exact formula) ----------------
__global__ __launch_bounds__(256) void k_ballq(const float* __restrict__ xyz,
                                               const float* __restrict__ new_xyz,
                                               int* __restrict__ ball_idx) {
  int b = blockIdx.y;
  int s = blockIdx.x * 4 + (threadIdx.x >> 6);
  int lane = threadIdx.x & 63;
  const float* pb = xyz + (size_t)b * N_ * 3;
  size_t q = (size_t)b * S_ + s;
  float qx = new_xyz[q * 3], qy = new_xyz[q * 3 + 1], qz = new_xyz[q * 3 + 2];
  float sq = __fadd_rn(__fadd_rn(__fmul_rn(qx, qx), __fmul_rn(qy, qy)), __fmul_rn(qz, qz));
  int* out = ball_idx + q * K_;
  int total = 0;
  int first_idx = -1;
  for (int basei = 0; basei < N_; basei += 64) {
    int i = basei + lane;
    float fx = pb[i * 3], fy = pb[i * 3 + 1], fz = pb[i * 3 + 2];
    float dot = __fmul_rn(qx, fx);
    dot = __fadd_rn(dot, __fmul_rn(qy, fy));
    dot = __fadd_rn(dot, __fmul_rn(qz, fz));
    float sd = __fadd_rn(__fadd_rn(__fmul_rn(fx, fx), __fmul_rn(fy, fy)), __fmul_rn(fz, fz));
    float dist = __fadd_rn(__fadd_rn(__fmul_rn(-2.0f, dot), sq), sd);
    bool within = (dist <= 0.36f);
    u64 m = __ballot(within);
    if (first_idx < 0 && m) first_idx = basei + __ffsll((long long)m) - 1;
    if (within) {
      int pos = total + __popcll(m & ((1ull << lane) - 1ull));
      if (pos < K_) out[pos] = i;
    }
    total += (int)__popcll(m);
    if (total >= K_) break;
  }
  if (total < K_) {
    int k2 = total + lane;
    if (k2 < K_) out[k2] = first_idx;
  }
}

// ============ MFMA layer kernels (unchanged from round 4) ============
#define MFMA(a, b, c) __builtin_amdgcn_mfma_f32_16x16x32_bf16(a, b, c, 0, 0, 0)

__global__ __launch_bounds__(256) void k_layer1(
    const float* __restrict__ xyz, const float* __restrict__ new_xyz,
    const unsigned short* __restrict__ featT, const int* __restrict__ ball_idx,
    const unsigned short* __restrict__ wbf0, const float* __restrict__ b0,
    unsigned short* __restrict__ y, float* __restrict__ stats) {
  __shared__ __align__(16) unsigned short Wl[128 * PITCH1];
  __shared__ __align__(16) unsigned short Gl[128 * PITCH1];
  __shared__ float sbias[128];
  int bb = blockIdx.y, s0 = blockIdx.x * 4, t = threadIdx.x;
  {
    int n = t >> 1, h = t & 1;
    const uint4* wr = (const uint4*)(wbf0 + n * 160 + h * 80);
    uint4* wl = (uint4*)(Wl + n * PITCH1 + h * 80);
    #pragma unroll
    for (int i = 0; i < 10; ++i) wl[i] = wr[i];
    if (t < 128) sbias[t] = b0[t];
  }
  {
    int r = t >> 1, h = t & 1;
    int q = r >> 5, ks = r & 31;
    size_t qg = (size_t)bb * S_ + s0 + q;
    int p = ball_idx[qg * K_ + ks]; if (p < 0) p = 0;
    const uint4* fr = (const uint4*)(featT + ((size_t)bb * N_ + p) * 128 + h * 64);
    uint4* gr = (uint4*)(Gl + r * PITCH1 + h * 64);
    #pragma unroll
    for (int i = 0; i < 8; ++i) gr[i] = fr[i];
    if (h == 0) {
      const float* pp = xyz + ((size_t)bb * N_ + p) * 3;
      Gl[r * PITCH1 + 128] = f2bf(pp[0] - new_xyz[qg * 3]);
      Gl[r * PITCH1 + 129] = f2bf(pp[1] - new_xyz[qg * 3 + 1]);
      Gl[r * PITCH1 + 130] = f2bf(pp[2] - new_xyz[qg * 3 + 2]);
    } else {
      for (int k = 131; k < 160; ++k) Gl[r * PITCH1 + k] = 0;
    }
  }
  __syncthreads();
  int w = t >> 6, L = t & 63, lm = L & 15, lg = L >> 4;
  f32x4 acc[2][8];
  #pragma unroll
  for (int mi = 0; mi < 2; ++mi)
    #pragma unroll
    for (int nt = 0; nt < 8; ++nt) acc[mi][nt] = (f32x4){0.f, 0.f, 0.f, 0.f};
  for (int kt = 0; kt < 5; ++kt) {
    int ko = kt * 32 + lg * 8;
    bf16x8 a0 = *(const bf16x8*)&Gl[(w * 32 + lm) * PITCH1 + ko];
    bf16x8 a1 = *(const bf16x8*)&Gl[(w * 32 + 16 + lm) * PITCH1 + ko];
    bf16x8 bv[8];
    #pragma unroll
    for (int nt = 0; nt < 8; ++nt)
      bv[nt] = *(const bf16x8*)&Wl[(nt * 16 + lm) * PITCH1 + ko];
    #pragma unroll
    for (int nt = 0; nt < 8; ++nt) {
      acc[0][nt] = MFMA(a0, bv[nt], acc[0][nt]);
      acc[1][nt] = MFMA(a1, bv[nt], acc[1][nt]);
    }
  }
  size_t qg = (size_t)bb * S_ + s0 + w;
  int slot = blockIdx.x & 31;
  #pragma unroll
  for (int nt = 0; nt < 8; ++nt) {
    int col = nt * 16 + lm;
    float bo = sbias[col];
    float s1 = 0.f, s2 = 0.f;
    #pragma unroll
    for (int mi = 0; mi < 2; ++mi)
      #pragma unroll
      for (int r = 0; r < 4; ++r) {
        float yv = acc[mi][nt][r] + bo;
        s1 += yv; s2 += yv * yv;
        int ks = mi * 16 + lg * 4 + r;
        y[(qg * K_ + ks) * 128 + col] = f2bf(yv);
      }
    s1 += __shfl_xor(s1, 16); s2 += __shfl_xor(s2, 16);
    s1 += __shfl_xor(s1, 32); s2 += __shfl_xor(s2, 32);
    if (lg == 0) {
      atomicAdd(stats + ((size_t)slot * 128 + col) * 2, s1);
      atomicAdd(stats + ((size_t)slot * 128 + col) * 2 + 1, s2);
    }
  }
}

__global__ void k_finalize(const float* __restrict__ stats, const float* __restrict__ gamma,
                           const float* __restrict__ beta, float* __restrict__ murs, int C) {
  for (int c = threadIdx.x; c < C; c += blockDim.x) {
    float s1 = 0.0f, s2 = 0.0f;
    for (int sl = 0; sl < 32; ++sl) {
      s1 += stats[((size_t)sl * C + c) * 2];
      s2 += stats[((size_t)sl * C + c) * 2 + 1];
    }
    const float inv = 1.0f / 524288.0f;  // 2^-19, exact
    float mu = s1 * inv;
    float var = s2 * inv - mu * mu;
    float a = gamma[c] * rsqrtf(var + 1e-5f);
    murs[c * 2] = a;
    murs[c * 2 + 1] = beta[c] - a * mu;
  }
}

__global__ __launch_bounds__(256) void k_layer2(
    unsigned short* y, const float* __restrict__ murs,
    const unsigned short* __restrict__ wbf1, const float* __restrict__ b1,
    float* __restrict__ stats) {
  __shared__ __align__(16) unsigned short Wl[128 * PITCH2];
  __shared__ __align__(16) unsigned short Gl[128 * PITCH2];
  __shared__ float sa[128], sd[128], sbias[128];
  int bb = blockIdx.y, s0 = blockIdx.x * 4, t = threadIdx.x;
  {
    int n = t >> 1, h = t & 1;
    const uint4* wr = (const uint4*)(wbf1 + n * 128 + h * 64);
    uint4* wl = (uint4*)(Wl + n * PITCH2 + h * 64);
    #pragma unroll
    for (int i = 0; i < 8; ++i) wl[i] = wr[i];
    if (t < 128) { sa[t] = murs[t * 2]; sd[t] = murs[t * 2 + 1]; sbias[t] = b1[t]; }
  }
  __syncthreads();
  {
    int r = t >> 1, h = t & 1;
    int q = r >> 5, ks = r & 31;
    size_t qg = (size_t)bb * S_ + s0 + q;
    const ushort4* yr = (const ushort4*)(y + (qg * K_ + ks) * 128 + h * 64);
    #pragma unroll
    for (int i = 0; i < 16; ++i) {
      ushort4 p = yr[i];
      int c = h * 64 + i * 4;
      ushort4 pk;
      pk.x = f2bf(fmaxf(sa[c]     * bf2f(p.x) + sd[c],     0.f));
      pk.y = f2bf(fmaxf(sa[c + 1] * bf2f(p.y) + sd[c + 1], 0.f));
      pk.z = f2bf(fmaxf(sa[c + 2] * bf2f(p.z) + sd[c + 2], 0.f));
      pk.w = f2bf(fmaxf(sa[c + 3] * bf2f(p.w) + sd[c + 3], 0.f));
      *(ushort4*)&Gl[r * PITCH2 + c] = pk;
    }
  }
  __syncthreads();
  int w = t >> 6, L = t & 63, lm = L & 15, lg = L >> 4;
  f32x4 acc[2][8];
  #pragma unroll
  for (int mi = 0; mi < 2; ++mi)
    #pragma unroll
    for (int nt = 0; nt < 8; ++nt) acc[mi][nt] = (f32x4){0.f, 0.f, 0.f, 0.f};
  for (int kt = 0; kt < 4; ++kt) {
    int ko = kt * 32 + lg * 8;
    bf16x8 a0 = *(const bf16x8*)&Gl[(w * 32 + lm) * PITCH2 + ko];
    bf16x8 a1 = *(const bf16x8*)&Gl[(w * 32 + 16 + lm) * PITCH2 + ko];
    bf16x8 bv[8];
    #pragma unroll
    for (int nt = 0; nt < 8; ++nt)
      bv[nt] = *(const bf16x8*)&Wl[(nt * 16 + lm) * PITCH2 + ko];
    #pragma unroll
    for (int nt = 0; nt < 8; ++nt) {
      acc[0][nt] = MFMA(a0, bv[nt], acc[0][nt]);
      acc[1][nt] = MFMA(a1, bv[nt], acc[1][nt]);
    }
  }
  size_t qg = (size_t)bb * S_ + s0 + w;
  int slot = blockIdx.x & 31;
  #pragma unroll
  for (int nt = 0; nt < 8; ++nt) {
    int col = nt * 16 + lm;
    float bo = sbias[col];
    float s1 = 0.f, s2 = 0.f;
    #pragma unroll
    for (int mi = 0; mi < 2; ++mi)
      #pragma unroll
      for (int r = 0; r < 4; ++r) {
        float yv = acc[mi][nt][r] + bo;
        s1 += yv; s2 += yv * yv;
        int ks = mi * 16 + lg * 4 + r;
        y[(qg * K_ + ks) * 128 + col] = f2bf(yv);
      }
    s1 += __shfl_xor(s1, 16); s2 += __shfl_xor(s2, 16);
    s1 += __shfl_xor(s1, 32); s2 += __shfl_xor(s2, 32);
    if (lg == 0) {
      atomicAdd(stats + ((size_t)slot * 128 + col) * 2, s1);
      atomicAdd(stats + ((size_t)slot * 128 + col) * 2 + 1, s2);
    }
  }
}

__global__ __launch_bounds__(256) void k_layer3(
    const unsigned short* __restrict__ y, const float* __restrict__ murs,
    const unsigned short* __restrict__ wbf2, const float* __restrict__ b2,
    unsigned short* __restrict__ ymax, unsigned short* __restrict__ ymin,
    float* __restrict__ stats) {
  __shared__ __align__(16) unsigned short Wl[128 * PITCH2];
  __shared__ __align__(16) unsigned short Gl[128 * PITCH2];
  __shared__ float sa[128], sd[128], sbias[128];
  int bb = blockIdx.y, s0 = blockIdx.x * 4, nh = blockIdx.z, t = threadIdx.x;
  {
    int n = t >> 1, h = t & 1;
    const uint4* wr = (const uint4*)(wbf2 + (size_t)(nh * 128 + n) * 128 + h * 64);
    uint4* wl = (uint4*)(Wl + n * PITCH2 + h * 64);
    #pragma unroll
    for (int i = 0; i < 8; ++i) wl[i] = wr[i];
    if (t < 128) { sa[t] = murs[t * 2]; sd[t] = murs[t * 2 + 1]; sbias[t] = b2[nh * 128 + t]; }
  }
  __syncthreads();
  {
    int r = t >> 1, h = t & 1;
    int q = r >> 5, ks = r & 31;
    size_t qg = (size_t)bb * S_ + s0 + q;
    const ushort4* yr = (const ushort4*)(y + (qg * K_ + ks) * 128 + h * 64);
    #pragma unroll
    for (int i = 0; i < 16; ++i) {
      ushort4 p = yr[i];
      int c = h * 64 + i * 4;
      ushort4 pk;
      pk.x = f2bf(fmaxf(sa[c]     * bf2f(p.x) + sd[c],     0.f));
      pk.y = f2bf(fmaxf(sa[c + 1] * bf2f(p.y) + sd[c + 1], 0.f));
      pk.z = f2bf(fmaxf(sa[c + 2] * bf2f(p.z) + sd[c + 2], 0.f));
      pk.w = f2bf(fmaxf(sa[c + 3] * bf2f(p.w) + sd[c + 3], 0.f));
      *(ushort4*)&Gl[r * PITCH2 + c] = pk;
    }
  }
  __syncthreads();
  int w = t >> 6, L = t & 63, lm = L & 15, lg = L >> 4;
  f32x4 acc[2][8];
  #pragma unroll
  for (int mi = 0; mi < 2; ++mi)
    #pragma unroll
    for (int nt = 0; nt < 8; ++nt) acc[mi][nt] = (f32x4){0.f, 0.f, 0.f, 0.f};
  for (int kt = 0; kt < 4; ++kt) {
    int ko = kt * 32 + lg * 8;
    bf16x8 a0 = *(const bf16x8*)&Gl[(w * 32 + lm) * PITCH2 + ko];
    bf16x8 a1 = *(const bf16x8*)&Gl[(w * 32 + 16 + lm) * PITCH2 + ko];
    bf16x8 bv[8];
    #pragma unroll
    for (int nt = 0; nt < 8; ++nt)
      bv[nt] = *(const bf16x8*)&Wl[(nt * 16 + lm) * PITCH2 + ko];
    #pragma unroll
    for (int nt = 0; nt < 8; ++nt) {
      acc[0][nt] = MFMA(a0, bv[nt], acc[0][nt]);
      acc[1][nt] = MFMA(a1, bv[nt], acc[1][nt]);
    }
  }
  size_t qg = (size_t)bb * S_ + s0 + w;
  int slot = blockIdx.x & 31;
  #pragma unroll
  for (int nt = 0; nt < 8; ++nt) {
    int col = nt * 16 + lm;
    int o = nh * 128 + col;
    float bo = sbias[col];
    float s1 = 0.f, s2 = 0.f, mx = -3.4e38f, mn = 3.4e38f;
    #pragma unroll
    for (int mi = 0; mi < 2; ++mi)
      #pragma unroll
      for (int r = 0; r < 4; ++r) {
        float yv = acc[mi][nt][r] + bo;
        s1 += yv; s2 += yv * yv;
        mx = fmaxf(mx, yv); mn = fminf(mn, yv);
      }
    s1 += __shfl_xor(s1, 16); s2 += __shfl_xor(s2, 16);
    s1 += __shfl_xor(s1, 32); s2 += __shfl_xor(s2, 32);
    mx = fmaxf(mx, __shfl_xor(mx, 16)); mx = fmaxf(mx, __shfl_xor(mx, 32));
    mn = fminf(mn, __shfl_xor(mn, 16)); mn = fminf(mn, __shfl_xor(mn, 32));
    if (lg == 0) {
      ymax[qg * 256 + o] = f2bf(mx);
      ymin[qg * 256 + o] = f2bf(mn);
      atomicAdd(stats + ((size_t)slot * 256 + o) * 2, s1);
      atomicAdd(stats + ((size_t)slot * 256 + o) * 2 + 1, s2);
    }
  }
}

__global__ __launch_bounds__(256) void k_final(const unsigned short* __restrict__ ymax,
                                               const unsigned short* __restrict__ ymin,
                                               const float* __restrict__ murs,
                                               float* __restrict__ out2) {
  __shared__ float tile[32][33];
  int b = blockIdx.z, o0 = blockIdx.y * 32, s0 = blockIdx.x * 32;
  int tx = threadIdx.x, ty = threadIdx.y;
  float a_rd = murs[(o0 + tx) * 2];
  #pragma unroll
  for (int j = 0; j < 32; j += 8) {
    size_t src = ((size_t)b * S_ + s0 + ty + j) * 256 + o0 + tx;
    tile[ty + j][tx] = (a_rd >= 0.0f) ? bf2f(ymax[src]) : bf2f(ymin[src]);
  }
  __syncthreads();
  #pragma unroll
  for (int j = 0; j < 32; j += 8) {
    int o = o0 + ty + j;
    float a = murs[o * 2], dd = murs[o * 2 + 1];
    out2[((size_t)b * 256 + o) * S_ + s0 + tx] = fmaxf(a * tile[tx][ty + j] + dd, 0.0f);
  }
}

extern "C" void kernel_launch(void* const* d_in, const int* in_sizes, int n_in,
                              void* d_out, int out_size, void* d_ws, size_t ws_size,
                              hipStream_t stream) {
  (void)in_sizes; (void)n_in; (void)out_size; (void)ws_size;
  const float* xyz  = (const float*)d_in[0];
  const float* feat = (const float*)d_in[1];
  const float* w0   = (const float*)d_in[2];
  const float* b0   = (const float*)d_in[3];
  const float* ga0  = (const float*)d_in[4];
  const float* be0  = (const float*)d_in[5];
  const float* w1   = (const float*)d_in[6];
  const float* b1   = (const float*)d_in[7];
  const float* ga1  = (const float*)d_in[8];
  const float* be1  = (const float*)d_in[9];
  const float* w2   = (const float*)d_in[10];
  const float* b2   = (const float*)d_in[11];
  const float* ga2  = (const float*)d_in[12];
  const float* be2  = (const float*)d_in[13];

  float* out_xyz  = (float*)d_out;
  float* out_feat = out_xyz + (size_t)B_ * S_ * 3;

  char* ws = (char*)d_ws;
  size_t off = 0;
  auto alloc = [&](size_t bytes) -> void* {
    void* p = ws + off;
    off += (bytes + 255) & ~(size_t)255;
    return p;
  };
  // Total ~170 MB
  unsigned short* featT = (unsigned short*)alloc((size_t)B_ * N_ * 128 * 2);  // 16.8 MB bf16
  int*   ball  = (int*)alloc((size_t)B_ * S_ * K_ * 4);                       // 2.1 MB
  float* stats = (float*)alloc(32768 * 4);
  float* murs1 = (float*)alloc(128 * 2 * 4);
  float* murs2 = (float*)alloc(128 * 2 * 4);
  float* murs3 = (float*)alloc(256 * 2 * 4);
  unsigned short* wbf0 = (unsigned short*)alloc(128 * 160 * 2);
  unsigned short* wbf1 = (unsigned short*)alloc(128 * 128 * 2);
  unsigned short* wbf2 = (unsigned short*)alloc(256 * 128 * 2);
  unsigned short* ymaxb = (unsigned short*)alloc((size_t)B_ * S_ * 256 * 2);  // 8.4 MB
  unsigned short* yminb = (unsigned short*)alloc((size_t)B_ * S_ * 256 * 2);  // 8.4 MB
  unsigned short* y = (unsigned short*)alloc((size_t)B_ * S_ * K_ * 128 * 2); // 134 MB (y1 then y2 in-place)

  // blocks: 16 fps | 16 init | 8192 transpose
  k_front<<<16 + 16 + 8192, 512, 0, stream>>>(xyz, out_xyz, feat, featT,
                                              w0, w1, w2, wbf0, wbf1, wbf2, stats);
  k_ballq<<<dim3(256, 16), 256, 0, stream>>>(xyz, out_xyz, ball);
  k_layer1<<<dim3(256, 16), 256, 0, stream>>>(xyz, out_xyz, featT, ball, wbf0, b0, y, stats);
  k_finalize<<<1, 256, 0, stream>>>(stats, ga0, be0, murs1, 128);
  k_layer2<<<dim3(256, 16), 256, 0, stream>>>(y, murs1, wbf1, b1, stats + 8192);
  k_finalize<<<1, 256, 0, stream>>>(stats + 8192, ga1, be1, murs2, 128);
  k_layer3<<<dim3(256, 16, 2), 256, 0, stream>>>(y, murs2, wbf2, b2, ymaxb, yminb, stats + 16384);
  k_finalize<<<1, 256, 0, stream>>>(stats + 16384, ga2, be2, murs3, 256);
  k_final<<<dim3(32, 8, 16), dim3(32, 8), 0, stream>>>(ymaxb, yminb, murs3, out_feat);
}